// Round 1
// baseline (693.609 us; speedup 1.0000x reference)
//
#include <hip/hip_runtime.h>

#define B_SZ   128
#define T_SEQ  256
#define C_DIM  384
#define HEADS  6
#define HD     64
#define WIN    64

// ---------------------------------------------------------------------------
// GEMM: C[M,N] = A[M,K] @ B[K,N] + bias[N].  fp32.
// 64x64 tile, K-chunk 16, 256 threads, 4x4 micro-tile per thread.
// M % 64 == 0, N % 64 == 0, K % 16 == 0 (holds: 32768, 1152/384, 384).
// ---------------------------------------------------------------------------
__global__ __launch_bounds__(256) void gemm_bias_f32(
    const float* __restrict__ A, const float* __restrict__ B,
    const float* __restrict__ bias, float* __restrict__ C,
    int M, int N, int K) {
  __shared__ float As[16][68];  // [k][m], padded: transpose-store, b128 reads
  __shared__ float Bs[16][64];  // [k][n]

  const int n0 = blockIdx.x * 64;
  const int m0 = blockIdx.y * 64;
  const int t  = threadIdx.x;
  const int tx = t & 15;        // col group
  const int ty = t >> 4;        // row group

  // global-load index maps
  const int am = t >> 2;        // 0..63  (A row within tile)
  const int ak = (t & 3) * 4;   // 0,4,8,12 (A k within chunk)
  const int bk = t >> 4;        // 0..15  (B k within chunk)
  const int bn = (t & 15) * 4;  // B col within tile

  float acc[4][4] = {{0.f}};

  for (int k0 = 0; k0 < K; k0 += 16) {
    float4 av = *(const float4*)(A + (size_t)(m0 + am) * K + k0 + ak);
    float4 bv = *(const float4*)(B + (size_t)(k0 + bk) * N + n0 + bn);
    __syncthreads();  // previous iteration's LDS reads complete
    As[ak + 0][am] = av.x;
    As[ak + 1][am] = av.y;
    As[ak + 2][am] = av.z;
    As[ak + 3][am] = av.w;
    *(float4*)(&Bs[bk][bn]) = bv;
    __syncthreads();
#pragma unroll
    for (int kk = 0; kk < 16; ++kk) {
      float4 a4 = *(const float4*)(&As[kk][ty * 4]);
      float4 b4 = *(const float4*)(&Bs[kk][tx * 4]);
      float a[4] = {a4.x, a4.y, a4.z, a4.w};
      float b[4] = {b4.x, b4.y, b4.z, b4.w};
#pragma unroll
      for (int i = 0; i < 4; ++i)
#pragma unroll
        for (int j = 0; j < 4; ++j) acc[i][j] += a[i] * b[j];
    }
  }

  float4 bb = *(const float4*)(bias + n0 + tx * 4);
  const float badd[4] = {bb.x, bb.y, bb.z, bb.w};
#pragma unroll
  for (int i = 0; i < 4; ++i) {
    float4 o;
    o.x = acc[i][0] + badd[0];
    o.y = acc[i][1] + badd[1];
    o.z = acc[i][2] + badd[2];
    o.w = acc[i][3] + badd[3];
    *(float4*)(C + (size_t)(m0 + ty * 4 + i) * N + n0 + tx * 4) = o;
  }
}

// ---------------------------------------------------------------------------
// Banded causal attention, fp32, flash-style over two 64-key chunks.
// Block = 256 threads = (16 tx) x (16 ty); handles (b, h, 64-query tile).
// LDS: Qs + K/P (reused) + Vs = 3 * 64*68*4 = 52.2 KB (static, < 64 KB).
// qkv layout: [B,T,1152], q at h*64, k at 384+h*64, v at 768+h*64.
// y layout: [B,T,384] (head-major within row), consumed by proj GEMM.
// ---------------------------------------------------------------------------
__global__ __launch_bounds__(256) void attn_local(
    const float* __restrict__ qkv, float* __restrict__ y) {
  __shared__ float Qs[64][68];
  __shared__ float KPs[64][68];  // K chunk, then reused for P
  __shared__ float Vs[64][68];

  const int bid = blockIdx.x;
  const int qt  = bid & 3;                 // query tile (T/64 = 4)
  const int h   = (bid >> 2) % HEADS;
  const int b   = bid / (4 * HEADS);
  const int t   = threadIdx.x;
  const int tx  = t & 15;
  const int ty  = t >> 4;

  const size_t rowbase = (size_t)b * T_SEQ * (3 * C_DIM);
  const int qoff = h * HD;
  const int koff = C_DIM + h * HD;
  const int voff = 2 * C_DIM + h * HD;
  const int qg0  = qt * 64;

  // ---- load Q tile: 64 rows x 64 dims ----
  {
    const int lr = t >> 4;          // 0..15
    const int ld = (t & 15) * 4;    // 0..60
#pragma unroll
    for (int u = 0; u < 4; ++u) {
      int r = lr + u * 16;
      float4 v4 = *(const float4*)(qkv + rowbase + (size_t)(qg0 + r) * (3 * C_DIM) + qoff + ld);
      *(float4*)(&Qs[r][ld]) = v4;
    }
  }

  float m_r[4], l_r[4], yacc[4][4];
#pragma unroll
  for (int i = 0; i < 4; ++i) {
    m_r[i] = -1e30f;
    l_r[i] = 0.f;
#pragma unroll
    for (int j = 0; j < 4; ++j) yacc[i][j] = 0.f;
  }

  const int nchunks  = (qt == 0) ? 1 : 2;
  const int kb_first = (qt == 0) ? 0 : (qg0 - 64);

  for (int ch = 0; ch < nchunks; ++ch) {
    const int kb = kb_first + ch * 64;

    // ---- load K,V chunk ----
    {
      const int lr = t >> 4;
      const int ld = (t & 15) * 4;
      __syncthreads();  // prior chunk's P/V reads complete before overwrite
#pragma unroll
      for (int u = 0; u < 4; ++u) {
        int r = lr + u * 16;
        size_t rb = rowbase + (size_t)(kb + r) * (3 * C_DIM);
        *(float4*)(&KPs[r][ld]) = *(const float4*)(qkv + rb + koff + ld);
        *(float4*)(&Vs[r][ld])  = *(const float4*)(qkv + rb + voff + ld);
      }
      __syncthreads();
    }

    // ---- scores: rows r = ty*4+i, cols c = tx + 16*j ----
    float s[4][4];
#pragma unroll
    for (int i = 0; i < 4; ++i)
#pragma unroll
      for (int j = 0; j < 4; ++j) s[i][j] = 0.f;

    for (int d = 0; d < 64; d += 4) {
      float4 q4[4], k4[4];
#pragma unroll
      for (int i = 0; i < 4; ++i) q4[i] = *(const float4*)(&Qs[ty * 4 + i][d]);
#pragma unroll
      for (int j = 0; j < 4; ++j) k4[j] = *(const float4*)(&KPs[tx + 16 * j][d]);
#pragma unroll
      for (int i = 0; i < 4; ++i)
#pragma unroll
        for (int j = 0; j < 4; ++j)
          s[i][j] += q4[i].x * k4[j].x + q4[i].y * k4[j].y +
                     q4[i].z * k4[j].z + q4[i].w * k4[j].w;
    }
    __syncthreads();  // all K reads done; KPs will be overwritten with P

    // ---- scale + band mask ----
#pragma unroll
    for (int i = 0; i < 4; ++i) {
      const int qg = qg0 + ty * 4 + i;
#pragma unroll
      for (int j = 0; j < 4; ++j) {
        const int kg = kb + tx + 16 * j;
        const bool valid = (kg <= qg) && (qg - kg <= WIN);
        s[i][j] = valid ? (s[i][j] * 0.125f) : -1e30f;
      }
    }

    // ---- chunk row-max (over j, then over tx lanes) ----
    float mc[4];
#pragma unroll
    for (int i = 0; i < 4; ++i) {
      mc[i] = fmaxf(fmaxf(s[i][0], s[i][1]), fmaxf(s[i][2], s[i][3]));
#pragma unroll
      for (int w = 1; w <= 8; w <<= 1) mc[i] = fmaxf(mc[i], __shfl_xor(mc[i], w));
    }

    // ---- online-softmax update ----
    float ls[4];
#pragma unroll
    for (int i = 0; i < 4; ++i) {
      const float mn    = fmaxf(m_r[i], mc[i]);
      const float alpha = __expf(m_r[i] - mn);
      m_r[i] = mn;
      l_r[i] *= alpha;
#pragma unroll
      for (int j = 0; j < 4; ++j) yacc[i][j] *= alpha;
      ls[i] = 0.f;
#pragma unroll
      for (int j = 0; j < 4; ++j) {
        const float p = __expf(s[i][j] - mn);
        s[i][j] = p;
        ls[i] += p;
      }
#pragma unroll
      for (int w = 1; w <= 8; w <<= 1) ls[i] += __shfl_xor(ls[i], w);
      l_r[i] += ls[i];
    }

    // ---- write P into KPs ----
#pragma unroll
    for (int i = 0; i < 4; ++i)
#pragma unroll
      for (int j = 0; j < 4; ++j) KPs[ty * 4 + i][tx + 16 * j] = s[i][j];
    __syncthreads();

    // ---- PV: yacc[i][j] += sum_c P[r][c] * V[c][d],  d = tx*4+j ----
    for (int c = 0; c < 64; c += 4) {
      float4 p4[4], v4[4];
#pragma unroll
      for (int i = 0; i < 4; ++i) p4[i] = *(const float4*)(&KPs[ty * 4 + i][c]);
#pragma unroll
      for (int cc = 0; cc < 4; ++cc) v4[cc] = *(const float4*)(&Vs[c + cc][tx * 4]);
#pragma unroll
      for (int i = 0; i < 4; ++i) {
        const float pa[4] = {p4[i].x, p4[i].y, p4[i].z, p4[i].w};
#pragma unroll
        for (int cc = 0; cc < 4; ++cc) {
          const float va[4] = {v4[cc].x, v4[cc].y, v4[cc].z, v4[cc].w};
#pragma unroll
          for (int j = 0; j < 4; ++j) yacc[i][j] += pa[cc] * va[j];
        }
      }
    }
  }

  // ---- epilogue: y = yacc / l ----
#pragma unroll
  for (int i = 0; i < 4; ++i) {
    const float inv = 1.f / l_r[i];
    float4 o;
    o.x = yacc[i][0] * inv;
    o.y = yacc[i][1] * inv;
    o.z = yacc[i][2] * inv;
    o.w = yacc[i][3] * inv;
    const int r = qg0 + ty * 4 + i;
    *(float4*)(y + ((size_t)(b * T_SEQ + r)) * C_DIM + h * HD + tx * 4) = o;
  }
}

// ---------------------------------------------------------------------------
extern "C" void kernel_launch(void* const* d_in, const int* in_sizes, int n_in,
                              void* d_out, int out_size, void* d_ws, size_t ws_size,
                              hipStream_t stream) {
  const float* x      = (const float*)d_in[0];
  const float* W_attn = (const float*)d_in[1];
  const float* b_attn = (const float*)d_in[2];
  const float* W_proj = (const float*)d_in[3];
  const float* b_proj = (const float*)d_in[4];
  float* out = (float*)d_out;

  const int M = B_SZ * T_SEQ;  // 32768
  float* qkv = (float*)d_ws;                       // M * 1152 fp32 = 151 MB
  float* y   = qkv + (size_t)M * (3 * C_DIM);      // M * 384  fp32 =  50 MB

  // 1) qkv = x @ W_attn + b_attn    [32768 x 1152]
  dim3 g1((3 * C_DIM) / 64, M / 64);
  gemm_bias_f32<<<g1, 256, 0, stream>>>(x, W_attn, b_attn, qkv, M, 3 * C_DIM, C_DIM);

  // 2) banded causal attention -> y [32768 x 384]
  attn_local<<<dim3(B_SZ * HEADS * (T_SEQ / 64)), 256, 0, stream>>>(qkv, y);

  // 3) out = y @ W_proj + b_proj   [32768 x 384]
  dim3 g2(C_DIM / 64, M / 64);
  gemm_bias_f32<<<g2, 256, 0, stream>>>(y, W_proj, b_proj, out, M, C_DIM, C_DIM);
}

// Round 2
// 293.420 us; speedup vs baseline: 2.3639x; 2.3639x over previous
//
#include <hip/hip_runtime.h>

#define B_SZ   128
#define T_SEQ  256
#define C_DIM  384
#define HEADS  6
#define HD     64
#define WIN    64

typedef __bf16 bf16x8 __attribute__((ext_vector_type(8)));
typedef float  f32x4  __attribute__((ext_vector_type(4)));

typedef __attribute__((address_space(3))) void lds_void;
typedef __attribute__((address_space(1))) void gbl_void;

__device__ __forceinline__ unsigned short f2bf(float f) {
  unsigned u = __float_as_uint(f);
  u += 0x7FFFu + ((u >> 16) & 1u);   // RNE (inputs are finite, no NaN care)
  return (unsigned short)(u >> 16);
}
__device__ __forceinline__ float bf2f(unsigned short h) {
  return __uint_as_float(((unsigned)h) << 16);
}

// ---------------------------------------------------------------------------
// fp32 -> bf16 elementwise convert (vectorized, n4 = nelems/4)
// ---------------------------------------------------------------------------
__global__ __launch_bounds__(256) void convert_f32_bf16(
    const float* __restrict__ in, unsigned short* __restrict__ out, int n4) {
  int i = blockIdx.x * blockDim.x + threadIdx.x;
  if (i < n4) {
    float4 v = ((const float4*)in)[i];
    ushort4 o;
    o.x = f2bf(v.x); o.y = f2bf(v.y); o.z = f2bf(v.z); o.w = f2bf(v.w);
    ((ushort4*)out)[i] = o;
  }
}

// ---------------------------------------------------------------------------
// W[K,N] fp32 -> Wt[N,K] bf16, 32x32 LDS tile transpose. K%32==0, N%32==0.
// ---------------------------------------------------------------------------
__global__ __launch_bounds__(256) void transpose_convert(
    const float* __restrict__ in, unsigned short* __restrict__ out,
    int K, int N) {
  __shared__ float tile[32][33];
  const int gx = blockIdx.x * 32;  // n
  const int gy = blockIdx.y * 32;  // k
  const int tx = threadIdx.x;      // 0..31
  const int ty = threadIdx.y;      // 0..7
#pragma unroll
  for (int r = ty; r < 32; r += 8)
    tile[r][tx] = in[(size_t)(gy + r) * N + gx + tx];
  __syncthreads();
#pragma unroll
  for (int r = ty; r < 32; r += 8)
    out[(size_t)(gx + r) * K + gy + tx] = f2bf(tile[tx][r]);
}

// ---------------------------------------------------------------------------
// bf16 MFMA GEMM: C[M,N] = A[M,K] @ Bt[N,K]^T + bias[N]
// 128x128 tile, BK=64, 256 thr = 4 waves (2x2), wave = 4x4 of 16x16x32 MFMA.
// global_load_lds width=16 staging (contiguous LDS layout, no padding).
// M%128==0, N%128==0, K%64==0.
// ---------------------------------------------------------------------------
template <bool OUT_BF16>
__global__ __launch_bounds__(256) void gemm_mfma_bf16(
    const unsigned short* __restrict__ A,   // [M,K] bf16
    const unsigned short* __restrict__ Bt,  // [N,K] bf16
    const float* __restrict__ bias,
    void* __restrict__ Cv, int M, int N, int K) {
  __shared__ unsigned short As[128 * 64];   // [m][k] contiguous, 16 KB
  __shared__ unsigned short Bs[128 * 64];   // [n][k] contiguous, 16 KB

  const int t    = threadIdx.x;
  const int lane = t & 63;
  const int w    = t >> 6;     // wave 0..3
  const int wm   = w & 1;      // wave m (0/1)
  const int wn   = w >> 1;     // wave n (0/1)
  const int m0   = blockIdx.y * 128;
  const int n0   = blockIdx.x * 128;

  const int lrow = lane >> 3;  // 0..7  (row within 8-row staging slab)
  const int lcol = lane & 7;   // 0..7  (16B chunk within 128B row)

  f32x4 acc[4][4];
#pragma unroll
  for (int i = 0; i < 4; ++i)
#pragma unroll
    for (int j = 0; j < 4; ++j) acc[i][j] = (f32x4){0.f, 0.f, 0.f, 0.f};

  const int mfrag = lane & 15;   // row within 16x16 tile (A/B frag)
  const int kq    = (lane >> 4) * 8;  // k offset of this lane's 8 elements

  for (int k0 = 0; k0 < K; k0 += 64) {
    // ---- stage A,B tiles: 16 insts each, 4 per wave, 8 rows per inst ----
#pragma unroll
    for (int i = 0; i < 4; ++i) {
      const int inst = w * 4 + i;
      const int r = inst * 8 + lrow;
      const unsigned short* ga = A  + (size_t)(m0 + r) * K + k0 + lcol * 8;
      const unsigned short* gb = Bt + (size_t)(n0 + r) * K + k0 + lcol * 8;
      __builtin_amdgcn_global_load_lds((const gbl_void*)ga,
                                       (lds_void*)(As + inst * 512), 16, 0, 0);
      __builtin_amdgcn_global_load_lds((const gbl_void*)gb,
                                       (lds_void*)(Bs + inst * 512), 16, 0, 0);
    }
    __syncthreads();

    // ---- compute: 2 k-steps of 32, 4x4 MFMA tiles ----
#pragma unroll
    for (int ks = 0; ks < 64; ks += 32) {
      bf16x8 af[4], bfr[4];
#pragma unroll
      for (int mt = 0; mt < 4; ++mt)
        af[mt] = *(const bf16x8*)(As + (size_t)(wm * 64 + mt * 16 + mfrag) * 64 + ks + kq);
#pragma unroll
      for (int nt = 0; nt < 4; ++nt)
        bfr[nt] = *(const bf16x8*)(Bs + (size_t)(wn * 64 + nt * 16 + mfrag) * 64 + ks + kq);
#pragma unroll
      for (int mt = 0; mt < 4; ++mt)
#pragma unroll
        for (int nt = 0; nt < 4; ++nt)
          acc[mt][nt] = __builtin_amdgcn_mfma_f32_16x16x32_bf16(
              af[mt], bfr[nt], acc[mt][nt], 0, 0, 0);
    }
    __syncthreads();
  }

  // ---- epilogue: C/D layout col=lane&15, row=(lane>>4)*4+reg ----
  const int ccol = lane & 15;
  const int crow = (lane >> 4) * 4;
#pragma unroll
  for (int nt = 0; nt < 4; ++nt) {
    const int col = n0 + wn * 64 + nt * 16 + ccol;
    const float bv = bias[col];
#pragma unroll
    for (int mt = 0; mt < 4; ++mt) {
#pragma unroll
      for (int r = 0; r < 4; ++r) {
        const int row = m0 + wm * 64 + mt * 16 + crow + r;
        const float val = acc[mt][nt][r] + bv;
        if (OUT_BF16)
          ((unsigned short*)Cv)[(size_t)row * N + col] = f2bf(val);
        else
          ((float*)Cv)[(size_t)row * N + col] = val;
      }
    }
  }
}

// ---------------------------------------------------------------------------
// Banded causal attention, fp32 compute, bf16 qkv in / bf16 y out.
// Block = 256 threads = (16 tx) x (16 ty); handles (b, h, 64-query tile).
// ---------------------------------------------------------------------------
__global__ __launch_bounds__(256) void attn_local(
    const unsigned short* __restrict__ qkv, unsigned short* __restrict__ y) {
  __shared__ float Qs[64][68];
  __shared__ float KPs[64][68];  // K chunk, then reused for P
  __shared__ float Vs[64][68];

  const int bid = blockIdx.x;
  const int qt  = bid & 3;                 // query tile (T/64 = 4)
  const int h   = (bid >> 2) % HEADS;
  const int b   = bid / (4 * HEADS);
  const int t   = threadIdx.x;
  const int tx  = t & 15;
  const int ty  = t >> 4;

  const size_t rowbase = (size_t)b * T_SEQ * (3 * C_DIM);
  const int qoff = h * HD;
  const int koff = C_DIM + h * HD;
  const int voff = 2 * C_DIM + h * HD;
  const int qg0  = qt * 64;

  // ---- load Q tile ----
  {
    const int lr = t >> 4;
    const int ld = (t & 15) * 4;
#pragma unroll
    for (int u = 0; u < 4; ++u) {
      int r = lr + u * 16;
      ushort4 v4 = *(const ushort4*)(qkv + rowbase + (size_t)(qg0 + r) * (3 * C_DIM) + qoff + ld);
      float4 f; f.x = bf2f(v4.x); f.y = bf2f(v4.y); f.z = bf2f(v4.z); f.w = bf2f(v4.w);
      *(float4*)(&Qs[r][ld]) = f;
    }
  }

  float m_r[4], l_r[4], yacc[4][4];
#pragma unroll
  for (int i = 0; i < 4; ++i) {
    m_r[i] = -1e30f;
    l_r[i] = 0.f;
#pragma unroll
    for (int j = 0; j < 4; ++j) yacc[i][j] = 0.f;
  }

  const int nchunks  = (qt == 0) ? 1 : 2;
  const int kb_first = (qt == 0) ? 0 : (qg0 - 64);

  for (int ch = 0; ch < nchunks; ++ch) {
    const int kb = kb_first + ch * 64;

    // ---- load K,V chunk ----
    {
      const int lr = t >> 4;
      const int ld = (t & 15) * 4;
      __syncthreads();
#pragma unroll
      for (int u = 0; u < 4; ++u) {
        int r = lr + u * 16;
        size_t rb = rowbase + (size_t)(kb + r) * (3 * C_DIM);
        ushort4 kv4 = *(const ushort4*)(qkv + rb + koff + ld);
        ushort4 vv4 = *(const ushort4*)(qkv + rb + voff + ld);
        float4 kf; kf.x = bf2f(kv4.x); kf.y = bf2f(kv4.y); kf.z = bf2f(kv4.z); kf.w = bf2f(kv4.w);
        float4 vf; vf.x = bf2f(vv4.x); vf.y = bf2f(vv4.y); vf.z = bf2f(vv4.z); vf.w = bf2f(vv4.w);
        *(float4*)(&KPs[r][ld]) = kf;
        *(float4*)(&Vs[r][ld])  = vf;
      }
      __syncthreads();
    }

    // ---- scores: rows r = ty*4+i, cols c = tx + 16*j ----
    float s[4][4];
#pragma unroll
    for (int i = 0; i < 4; ++i)
#pragma unroll
      for (int j = 0; j < 4; ++j) s[i][j] = 0.f;

    for (int d = 0; d < 64; d += 4) {
      float4 q4[4], k4[4];
#pragma unroll
      for (int i = 0; i < 4; ++i) q4[i] = *(const float4*)(&Qs[ty * 4 + i][d]);
#pragma unroll
      for (int j = 0; j < 4; ++j) k4[j] = *(const float4*)(&KPs[tx + 16 * j][d]);
#pragma unroll
      for (int i = 0; i < 4; ++i)
#pragma unroll
        for (int j = 0; j < 4; ++j)
          s[i][j] += q4[i].x * k4[j].x + q4[i].y * k4[j].y +
                     q4[i].z * k4[j].z + q4[i].w * k4[j].w;
    }
    __syncthreads();

    // ---- scale + band mask ----
#pragma unroll
    for (int i = 0; i < 4; ++i) {
      const int qg = qg0 + ty * 4 + i;
#pragma unroll
      for (int j = 0; j < 4; ++j) {
        const int kg = kb + tx + 16 * j;
        const bool valid = (kg <= qg) && (qg - kg <= WIN);
        s[i][j] = valid ? (s[i][j] * 0.125f) : -1e30f;
      }
    }

    // ---- chunk row-max ----
    float mc[4];
#pragma unroll
    for (int i = 0; i < 4; ++i) {
      mc[i] = fmaxf(fmaxf(s[i][0], s[i][1]), fmaxf(s[i][2], s[i][3]));
#pragma unroll
      for (int w = 1; w <= 8; w <<= 1) mc[i] = fmaxf(mc[i], __shfl_xor(mc[i], w));
    }

    // ---- online-softmax update ----
    float ls[4];
#pragma unroll
    for (int i = 0; i < 4; ++i) {
      const float mn    = fmaxf(m_r[i], mc[i]);
      const float alpha = __expf(m_r[i] - mn);
      m_r[i] = mn;
      l_r[i] *= alpha;
#pragma unroll
      for (int j = 0; j < 4; ++j) yacc[i][j] *= alpha;
      ls[i] = 0.f;
#pragma unroll
      for (int j = 0; j < 4; ++j) {
        const float p = __expf(s[i][j] - mn);
        s[i][j] = p;
        ls[i] += p;
      }
#pragma unroll
      for (int w = 1; w <= 8; w <<= 1) ls[i] += __shfl_xor(ls[i], w);
      l_r[i] += ls[i];
    }

    // ---- write P into KPs ----
#pragma unroll
    for (int i = 0; i < 4; ++i)
#pragma unroll
      for (int j = 0; j < 4; ++j) KPs[ty * 4 + i][tx + 16 * j] = s[i][j];
    __syncthreads();

    // ---- PV ----
    for (int c = 0; c < 64; c += 4) {
      float4 p4[4], v4[4];
#pragma unroll
      for (int i = 0; i < 4; ++i) p4[i] = *(const float4*)(&KPs[ty * 4 + i][c]);
#pragma unroll
      for (int cc = 0; cc < 4; ++cc) v4[cc] = *(const float4*)(&Vs[c + cc][tx * 4]);
#pragma unroll
      for (int i = 0; i < 4; ++i) {
        const float pa[4] = {p4[i].x, p4[i].y, p4[i].z, p4[i].w};
#pragma unroll
        for (int cc = 0; cc < 4; ++cc) {
          const float va[4] = {v4[cc].x, v4[cc].y, v4[cc].z, v4[cc].w};
#pragma unroll
          for (int j = 0; j < 4; ++j) yacc[i][j] += pa[cc] * va[j];
        }
      }
    }
  }

  // ---- epilogue: y(bf16) = yacc / l ----
#pragma unroll
  for (int i = 0; i < 4; ++i) {
    const float inv = 1.f / l_r[i];
    ushort4 o;
    o.x = f2bf(yacc[i][0] * inv);
    o.y = f2bf(yacc[i][1] * inv);
    o.z = f2bf(yacc[i][2] * inv);
    o.w = f2bf(yacc[i][3] * inv);
    const int r = qg0 + ty * 4 + i;
    *(ushort4*)(y + ((size_t)(b * T_SEQ + r)) * C_DIM + h * HD + tx * 4) = o;
  }
}

// ---------------------------------------------------------------------------
extern "C" void kernel_launch(void* const* d_in, const int* in_sizes, int n_in,
                              void* d_out, int out_size, void* d_ws, size_t ws_size,
                              hipStream_t stream) {
  const float* x      = (const float*)d_in[0];
  const float* W_attn = (const float*)d_in[1];
  const float* b_attn = (const float*)d_in[2];
  const float* W_proj = (const float*)d_in[3];
  const float* b_proj = (const float*)d_in[4];
  float* out = (float*)d_out;

  const int M = B_SZ * T_SEQ;  // 32768

  unsigned short* qkv_b = (unsigned short*)d_ws;            // M*1152 bf16
  unsigned short* y_b   = qkv_b + (size_t)M * (3 * C_DIM);  // M*384
  unsigned short* x_b   = y_b   + (size_t)M * C_DIM;        // M*384
  unsigned short* Wa_t  = x_b   + (size_t)M * C_DIM;        // 1152*384
  unsigned short* Wp_t  = Wa_t  + (size_t)(3 * C_DIM) * C_DIM;  // 384*384

  // 0) converts
  {
    int n4 = M * C_DIM / 4;
    convert_f32_bf16<<<n4 / 256, 256, 0, stream>>>(x, x_b, n4);
    transpose_convert<<<dim3((3 * C_DIM) / 32, C_DIM / 32), dim3(32, 8), 0, stream>>>(
        W_attn, Wa_t, C_DIM, 3 * C_DIM);
    transpose_convert<<<dim3(C_DIM / 32, C_DIM / 32), dim3(32, 8), 0, stream>>>(
        W_proj, Wp_t, C_DIM, C_DIM);
  }

  // 1) qkv(bf16) = x @ W_attn + b_attn   [32768 x 1152]
  gemm_mfma_bf16<true><<<dim3((3 * C_DIM) / 128, M / 128), 256, 0, stream>>>(
      x_b, Wa_t, b_attn, qkv_b, M, 3 * C_DIM, C_DIM);

  // 2) banded causal attention -> y(bf16) [32768 x 384]
  attn_local<<<dim3(B_SZ * HEADS * (T_SEQ / 64)), 256, 0, stream>>>(qkv_b, y_b);

  // 3) out(fp32) = y @ W_proj + b_proj   [32768 x 384]
  gemm_mfma_bf16<false><<<dim3(C_DIM / 128, M / 128), 256, 0, stream>>>(
      y_b, Wp_t, b_proj, out, M, C_DIM, C_DIM);
}

// Round 3
// 232.557 us; speedup vs baseline: 2.9825x; 1.2617x over previous
//
#include <hip/hip_runtime.h>

#define B_SZ   128
#define T_SEQ  256
#define C_DIM  384
#define HEADS  6
#define HD     64
#define WIN    64

typedef __bf16 bf16x8 __attribute__((ext_vector_type(8)));
typedef float  f32x4  __attribute__((ext_vector_type(4)));

typedef __attribute__((address_space(3))) void lds_void;
typedef __attribute__((address_space(1))) void gbl_void;

__device__ __forceinline__ unsigned short f2bf(float f) {
  unsigned u = __float_as_uint(f);
  u += 0x7FFFu + ((u >> 16) & 1u);   // RNE
  return (unsigned short)(u >> 16);
}

// ---------------------------------------------------------------------------
// fp32 -> bf16 elementwise convert (vectorized, n4 = nelems/4)
// ---------------------------------------------------------------------------
__global__ __launch_bounds__(256) void convert_f32_bf16(
    const float* __restrict__ in, unsigned short* __restrict__ out, int n4) {
  int i = blockIdx.x * blockDim.x + threadIdx.x;
  if (i < n4) {
    float4 v = ((const float4*)in)[i];
    ushort4 o;
    o.x = f2bf(v.x); o.y = f2bf(v.y); o.z = f2bf(v.z); o.w = f2bf(v.w);
    ((ushort4*)out)[i] = o;
  }
}

// ---------------------------------------------------------------------------
// W[K,N] fp32 -> Wt[N,K] bf16, 32x32 LDS tile transpose.
// ---------------------------------------------------------------------------
__global__ __launch_bounds__(256) void transpose_convert(
    const float* __restrict__ in, unsigned short* __restrict__ out,
    int K, int N) {
  __shared__ float tile[32][33];
  const int gx = blockIdx.x * 32;  // n
  const int gy = blockIdx.y * 32;  // k
  const int tx = threadIdx.x;      // 0..31
  const int ty = threadIdx.y;      // 0..7
#pragma unroll
  for (int r = ty; r < 32; r += 8)
    tile[r][tx] = in[(size_t)(gy + r) * N + gx + tx];
  __syncthreads();
#pragma unroll
  for (int r = ty; r < 32; r += 8)
    out[(size_t)(gx + r) * K + gy + tx] = f2bf(tile[tx][r]);
}

// ---------------------------------------------------------------------------
// bf16 MFMA GEMM: C[M,N] = A[M,K] @ Bt[N,K]^T + bias[N]
// 128x128 tile, BK=64, 256 thr = 4 waves (2x2), wave = 4x4 of 16x16x32 MFMA.
// ---------------------------------------------------------------------------
template <bool OUT_BF16>
__global__ __launch_bounds__(256) void gemm_mfma_bf16(
    const unsigned short* __restrict__ A,   // [M,K] bf16
    const unsigned short* __restrict__ Bt,  // [N,K] bf16
    const float* __restrict__ bias,
    void* __restrict__ Cv, int M, int N, int K) {
  __shared__ unsigned short As[128 * 64];
  __shared__ unsigned short Bs[128 * 64];

  const int t    = threadIdx.x;
  const int lane = t & 63;
  const int w    = t >> 6;
  const int wm   = w & 1;
  const int wn   = w >> 1;
  const int m0   = blockIdx.y * 128;
  const int n0   = blockIdx.x * 128;

  const int lrow = lane >> 3;
  const int lcol = lane & 7;

  f32x4 acc[4][4];
#pragma unroll
  for (int i = 0; i < 4; ++i)
#pragma unroll
    for (int j = 0; j < 4; ++j) acc[i][j] = (f32x4){0.f, 0.f, 0.f, 0.f};

  const int mfrag = lane & 15;
  const int kq    = (lane >> 4) * 8;

  for (int k0 = 0; k0 < K; k0 += 64) {
#pragma unroll
    for (int i = 0; i < 4; ++i) {
      const int inst = w * 4 + i;
      const int r = inst * 8 + lrow;
      const unsigned short* ga = A  + (size_t)(m0 + r) * K + k0 + lcol * 8;
      const unsigned short* gb = Bt + (size_t)(n0 + r) * K + k0 + lcol * 8;
      __builtin_amdgcn_global_load_lds((const gbl_void*)ga,
                                       (lds_void*)(As + inst * 512), 16, 0, 0);
      __builtin_amdgcn_global_load_lds((const gbl_void*)gb,
                                       (lds_void*)(Bs + inst * 512), 16, 0, 0);
    }
    __syncthreads();

#pragma unroll
    for (int ks = 0; ks < 64; ks += 32) {
      bf16x8 af[4], bfr[4];
#pragma unroll
      for (int mt = 0; mt < 4; ++mt)
        af[mt] = *(const bf16x8*)(As + (size_t)(wm * 64 + mt * 16 + mfrag) * 64 + ks + kq);
#pragma unroll
      for (int nt = 0; nt < 4; ++nt)
        bfr[nt] = *(const bf16x8*)(Bs + (size_t)(wn * 64 + nt * 16 + mfrag) * 64 + ks + kq);
#pragma unroll
      for (int mt = 0; mt < 4; ++mt)
#pragma unroll
        for (int nt = 0; nt < 4; ++nt)
          acc[mt][nt] = __builtin_amdgcn_mfma_f32_16x16x32_bf16(
              af[mt], bfr[nt], acc[mt][nt], 0, 0, 0);
    }
    __syncthreads();
  }

  const int ccol = lane & 15;
  const int crow = (lane >> 4) * 4;
#pragma unroll
  for (int nt = 0; nt < 4; ++nt) {
    const int col = n0 + wn * 64 + nt * 16 + ccol;
    const float bv = bias[col];
#pragma unroll
    for (int mt = 0; mt < 4; ++mt) {
#pragma unroll
      for (int r = 0; r < 4; ++r) {
        const int row = m0 + wm * 64 + mt * 16 + crow + r;
        const float val = acc[mt][nt][r] + bv;
        if (OUT_BF16)
          ((unsigned short*)Cv)[(size_t)row * N + col] = f2bf(val);
        else
          ((float*)Cv)[(size_t)row * N + col] = val;
      }
    }
  }
}

// ---------------------------------------------------------------------------
// Banded causal attention via bf16 MFMA, fp32 softmax.
// Block = 256 thr = 4 waves; wave w owns q-rows [w*16, w*16+16) of a 64-row
// query tile. Per chunk (64 keys): QK^T (8 MFMA) -> softmax in C-layout ->
// P round-trip through per-wave LDS (fp32, stride 68) -> PV (8 MFMA).
// ---------------------------------------------------------------------------
#define PSTR 68
__global__ __launch_bounds__(256) void attn_mfma(
    const unsigned short* __restrict__ qkv, unsigned short* __restrict__ y) {
  __shared__ unsigned short Qs[64 * 64];   // [qrow][d]  bf16
  __shared__ unsigned short Ks[64 * 64];   // [key][d]   bf16
  __shared__ unsigned short Vt[64 * 64];   // [d][key]   bf16 (transposed)
  __shared__ float Pw[4][16 * PSTR];       // per-wave P [qrow16][key64]

  const int bid = blockIdx.x;
  const int qt  = bid & 3;
  const int h   = (bid >> 2) % HEADS;
  const int b   = bid / (4 * HEADS);
  const int t   = threadIdx.x;
  const int lane = t & 63;
  const int w    = t >> 6;
  const int quad = lane >> 4;
  const int m16  = lane & 15;

  const size_t rowbase = (size_t)b * T_SEQ * (3 * C_DIM);
  const int qoff = h * HD;
  const int koff = C_DIM + h * HD;
  const int voff = 2 * C_DIM + h * HD;
  const int qg0  = qt * 64;

  // ---- stage Q (64x64 bf16) via global_load_lds, 2 insts/wave ----
  {
    const int lrow = lane >> 3;
    const int lcol = lane & 7;
#pragma unroll
    for (int i = 0; i < 2; ++i) {
      const int inst = w * 2 + i;
      const int r = inst * 8 + lrow;
      const unsigned short* ga =
          qkv + rowbase + (size_t)(qg0 + r) * (3 * C_DIM) + qoff + lcol * 8;
      __builtin_amdgcn_global_load_lds((const gbl_void*)ga,
                                       (lds_void*)(Qs + inst * 512), 16, 0, 0);
    }
  }

  float m_r[4], l_r[4];
  f32x4 yacc[4];  // [d-tile]; regs = rows quad*4+r, col = m16
#pragma unroll
  for (int r = 0; r < 4; ++r) { m_r[r] = -1e30f; l_r[r] = 0.f; }
#pragma unroll
  for (int dt = 0; dt < 4; ++dt) yacc[dt] = (f32x4){0.f, 0.f, 0.f, 0.f};

  const int nchunks  = (qt == 0) ? 1 : 2;
  const int kb_first = (qt == 0) ? 0 : (qg0 - 64);
  const int qrow_base = qg0 + w * 16 + quad * 4;

  for (int ch = 0; ch < nchunks; ++ch) {
    const int kb = kb_first + ch * 64;

    __syncthreads();  // drain Q/K staging; protect Ks/Vt/Pw from prior reads

    // ---- stage K via global_load_lds ----
    {
      const int lrow = lane >> 3;
      const int lcol = lane & 7;
#pragma unroll
      for (int i = 0; i < 2; ++i) {
        const int inst = w * 2 + i;
        const int r = inst * 8 + lrow;
        const unsigned short* ga =
            qkv + rowbase + (size_t)(kb + r) * (3 * C_DIM) + koff + lcol * 8;
        __builtin_amdgcn_global_load_lds((const gbl_void*)ga,
                                         (lds_void*)(Ks + inst * 512), 16, 0, 0);
      }
    }
    // ---- stage V transposed (VALU loads + scatter b16 writes, 2-way free) ----
    {
      const int vkey = t & 63;
      const int vd0  = (t >> 6) * 16;
      const unsigned short* gv =
          qkv + rowbase + (size_t)(kb + vkey) * (3 * C_DIM) + voff + vd0;
#pragma unroll
      for (int u = 0; u < 4; ++u) {
        ushort4 vv = *(const ushort4*)(gv + u * 4);
        Vt[(vd0 + u * 4 + 0) * 64 + vkey] = vv.x;
        Vt[(vd0 + u * 4 + 1) * 64 + vkey] = vv.y;
        Vt[(vd0 + u * 4 + 2) * 64 + vkey] = vv.z;
        Vt[(vd0 + u * 4 + 3) * 64 + vkey] = vv.w;
      }
    }
    __syncthreads();

    // ---- QK^T: S[16q x 64key], 4 n-tiles x 2 k-steps ----
    f32x4 sacc[4];
#pragma unroll
    for (int nt = 0; nt < 4; ++nt) sacc[nt] = (f32x4){0.f, 0.f, 0.f, 0.f};
#pragma unroll
    for (int ks = 0; ks < 64; ks += 32) {
      bf16x8 aq = *(const bf16x8*)(Qs + (size_t)(w * 16 + m16) * 64 + ks + quad * 8);
#pragma unroll
      for (int nt = 0; nt < 4; ++nt) {
        bf16x8 kf = *(const bf16x8*)(Ks + (size_t)(nt * 16 + m16) * 64 + ks + quad * 8);
        sacc[nt] = __builtin_amdgcn_mfma_f32_16x16x32_bf16(aq, kf, sacc[nt], 0, 0, 0);
      }
    }

    // ---- scale + band mask (C-layout: row=quad*4+r, col=m16) ----
    float mc[4] = {-1e30f, -1e30f, -1e30f, -1e30f};
#pragma unroll
    for (int nt = 0; nt < 4; ++nt) {
      const int kg = kb + nt * 16 + m16;
#pragma unroll
      for (int r = 0; r < 4; ++r) {
        const int qg = qrow_base + r;
        const bool valid = (kg <= qg) && (qg - kg <= WIN);
        const float sv = valid ? (sacc[nt][r] * 0.125f) : -1e30f;
        sacc[nt][r] = sv;
        mc[r] = fmaxf(mc[r], sv);
      }
    }
#pragma unroll
    for (int r = 0; r < 4; ++r) {
#pragma unroll
      for (int x = 1; x <= 8; x <<= 1) mc[r] = fmaxf(mc[r], __shfl_xor(mc[r], x));
    }

    // ---- online softmax update ----
#pragma unroll
    for (int r = 0; r < 4; ++r) {
      const float mn    = fmaxf(m_r[r], mc[r]);
      const float alpha = __expf(m_r[r] - mn);
      m_r[r] = mn;
      l_r[r] *= alpha;
#pragma unroll
      for (int dt = 0; dt < 4; ++dt) yacc[dt][r] *= alpha;
      float ls = 0.f;
#pragma unroll
      for (int nt = 0; nt < 4; ++nt) {
        const float p = __expf(sacc[nt][r] - mn);
        sacc[nt][r] = p;
        ls += p;
      }
#pragma unroll
      for (int x = 1; x <= 8; x <<= 1) ls += __shfl_xor(ls, x);
      l_r[r] += ls;
    }

    // ---- write P (fp32) to per-wave LDS ----
#pragma unroll
    for (int nt = 0; nt < 4; ++nt)
#pragma unroll
      for (int r = 0; r < 4; ++r)
        Pw[w][(quad * 4 + r) * PSTR + nt * 16 + m16] = sacc[nt][r];
    __syncthreads();

    // ---- PV: A = P-frag (fp32->bf16), B = Vt-frag ----
#pragma unroll
    for (int ks = 0; ks < 64; ks += 32) {
      f32x4 pa = *(const f32x4*)(&Pw[w][m16 * PSTR + ks + quad * 8]);
      f32x4 pb = *(const f32x4*)(&Pw[w][m16 * PSTR + ks + quad * 8 + 4]);
      bf16x8 ap;
#pragma unroll
      for (int j = 0; j < 4; ++j) {
        ap[j]     = (__bf16)pa[j];
        ap[4 + j] = (__bf16)pb[j];
      }
#pragma unroll
      for (int dt = 0; dt < 4; ++dt) {
        bf16x8 vf = *(const bf16x8*)(Vt + (size_t)(dt * 16 + m16) * 64 + ks + quad * 8);
        yacc[dt] = __builtin_amdgcn_mfma_f32_16x16x32_bf16(ap, vf, yacc[dt], 0, 0, 0);
      }
    }
  }

  // ---- epilogue: y(bf16) = yacc / l ----
  float inv[4];
#pragma unroll
  for (int r = 0; r < 4; ++r) inv[r] = 1.f / l_r[r];
#pragma unroll
  for (int dt = 0; dt < 4; ++dt) {
#pragma unroll
    for (int r = 0; r < 4; ++r) {
      const int row = qrow_base + r;
      y[((size_t)(b * T_SEQ + row)) * C_DIM + h * HD + dt * 16 + m16] =
          f2bf(yacc[dt][r] * inv[r]);
    }
  }
}

// ---------------------------------------------------------------------------
extern "C" void kernel_launch(void* const* d_in, const int* in_sizes, int n_in,
                              void* d_out, int out_size, void* d_ws, size_t ws_size,
                              hipStream_t stream) {
  const float* x      = (const float*)d_in[0];
  const float* W_attn = (const float*)d_in[1];
  const float* b_attn = (const float*)d_in[2];
  const float* W_proj = (const float*)d_in[3];
  const float* b_proj = (const float*)d_in[4];
  float* out = (float*)d_out;

  const int M = B_SZ * T_SEQ;  // 32768

  unsigned short* qkv_b = (unsigned short*)d_ws;            // M*1152 bf16
  unsigned short* y_b   = qkv_b + (size_t)M * (3 * C_DIM);  // M*384
  unsigned short* x_b   = y_b   + (size_t)M * C_DIM;        // M*384
  unsigned short* Wa_t  = x_b   + (size_t)M * C_DIM;        // 1152*384
  unsigned short* Wp_t  = Wa_t  + (size_t)(3 * C_DIM) * C_DIM;  // 384*384

  // 0) converts
  {
    int n4 = M * C_DIM / 4;
    convert_f32_bf16<<<n4 / 256, 256, 0, stream>>>(x, x_b, n4);
    transpose_convert<<<dim3((3 * C_DIM) / 32, C_DIM / 32), dim3(32, 8), 0, stream>>>(
        W_attn, Wa_t, C_DIM, 3 * C_DIM);
    transpose_convert<<<dim3(C_DIM / 32, C_DIM / 32), dim3(32, 8), 0, stream>>>(
        W_proj, Wp_t, C_DIM, C_DIM);
  }

  // 1) qkv(bf16) = x @ W_attn + b_attn   [32768 x 1152]
  gemm_mfma_bf16<true><<<dim3((3 * C_DIM) / 128, M / 128), 256, 0, stream>>>(
      x_b, Wa_t, b_attn, qkv_b, M, 3 * C_DIM, C_DIM);

  // 2) banded causal attention -> y(bf16) [32768 x 384]
  attn_mfma<<<dim3(B_SZ * HEADS * (T_SEQ / 64)), 256, 0, stream>>>(qkv_b, y_b);

  // 3) out(fp32) = y @ W_proj + b_proj   [32768 x 384]
  gemm_mfma_bf16<false><<<dim3(C_DIM / 128, M / 128), 256, 0, stream>>>(
      y_b, Wp_t, b_proj, out, M, C_DIM, C_DIM);
}

// Round 4
// 224.658 us; speedup vs baseline: 3.0874x; 1.0352x over previous
//
#include <hip/hip_runtime.h>

#define B_SZ   128
#define T_SEQ  256
#define C_DIM  384
#define HEADS  6
#define HD     64
#define WIN    64

typedef __bf16 bf16x8 __attribute__((ext_vector_type(8)));
typedef float  f32x4  __attribute__((ext_vector_type(4)));

typedef __attribute__((address_space(3))) void lds_void;
typedef __attribute__((address_space(1))) void gbl_void;

__device__ __forceinline__ unsigned short f2bf(float f) {
  unsigned u = __float_as_uint(f);
  u += 0x7FFFu + ((u >> 16) & 1u);   // RNE
  return (unsigned short)(u >> 16);
}

// ---------------------------------------------------------------------------
// fp32 -> bf16 elementwise convert (vectorized, n4 = nelems/4)
// ---------------------------------------------------------------------------
__global__ __launch_bounds__(256) void convert_f32_bf16(
    const float* __restrict__ in, unsigned short* __restrict__ out, int n4) {
  int i = blockIdx.x * blockDim.x + threadIdx.x;
  if (i < n4) {
    float4 v = ((const float4*)in)[i];
    ushort4 o;
    o.x = f2bf(v.x); o.y = f2bf(v.y); o.z = f2bf(v.z); o.w = f2bf(v.w);
    ((ushort4*)out)[i] = o;
  }
}

// ---------------------------------------------------------------------------
// W[K,N] fp32 -> Wt[N,K] bf16, 32x32 LDS tile transpose.
// ---------------------------------------------------------------------------
__global__ __launch_bounds__(256) void transpose_convert(
    const float* __restrict__ in, unsigned short* __restrict__ out,
    int K, int N) {
  __shared__ float tile[32][33];
  const int gx = blockIdx.x * 32;  // n
  const int gy = blockIdx.y * 32;  // k
  const int tx = threadIdx.x;      // 0..31
  const int ty = threadIdx.y;      // 0..7
#pragma unroll
  for (int r = ty; r < 32; r += 8)
    tile[r][tx] = in[(size_t)(gy + r) * N + gx + tx];
  __syncthreads();
#pragma unroll
  for (int r = ty; r < 32; r += 8)
    out[(size_t)(gx + r) * K + gy + tx] = f2bf(tile[tx][r]);
}

// ---------------------------------------------------------------------------
// bf16 MFMA GEMM: C[M,N] = A[M,K] @ Bt[N,K]^T + bias[N]
// 128x128 tile, BK=64, 256 thr = 4 waves (2x2), wave = 4x4 of 16x16x32 MFMA.
// XOR-swizzled LDS: lane l stages global chunk (l&7)^(l>>3), so
// LDS[row][pos p] = global chunk p ^ (row&7); frag reads spread all 32 banks.
// ---------------------------------------------------------------------------
template <bool OUT_BF16>
__global__ __launch_bounds__(256) void gemm_mfma_bf16(
    const unsigned short* __restrict__ A,   // [M,K] bf16
    const unsigned short* __restrict__ Bt,  // [N,K] bf16
    const float* __restrict__ bias,
    void* __restrict__ Cv, int M, int N, int K) {
  __shared__ unsigned short As[128 * 64];
  __shared__ unsigned short Bs[128 * 64];

  const int t    = threadIdx.x;
  const int lane = t & 63;
  const int w    = t >> 6;
  const int wm   = w & 1;
  const int wn   = w >> 1;
  const int m0   = blockIdx.y * 128;
  const int n0   = blockIdx.x * 128;

  const int lrow = lane >> 3;         // 0..7 row within 8-row slab
  const int lcol = lane & 7;          // 0..7 LDS 16B-position
  const int schunk = lcol ^ lrow;     // swizzled global chunk this lane fetches

  f32x4 acc[4][4];
#pragma unroll
  for (int i = 0; i < 4; ++i)
#pragma unroll
    for (int j = 0; j < 4; ++j) acc[i][j] = (f32x4){0.f, 0.f, 0.f, 0.f};

  const int mfrag = lane & 15;
  const int quad  = lane >> 4;
  const int sw    = mfrag & 7;        // row&7 for all frag rows

  for (int k0 = 0; k0 < K; k0 += 64) {
#pragma unroll
    for (int i = 0; i < 4; ++i) {
      const int inst = w * 4 + i;
      const int r = inst * 8 + lrow;
      const unsigned short* ga = A  + (size_t)(m0 + r) * K + k0 + schunk * 8;
      const unsigned short* gb = Bt + (size_t)(n0 + r) * K + k0 + schunk * 8;
      __builtin_amdgcn_global_load_lds((const gbl_void*)ga,
                                       (lds_void*)(As + inst * 512), 16, 0, 0);
      __builtin_amdgcn_global_load_lds((const gbl_void*)gb,
                                       (lds_void*)(Bs + inst * 512), 16, 0, 0);
    }
    __syncthreads();

#pragma unroll
    for (int ks = 0; ks < 64; ks += 32) {
      const int cg = (ks >> 3) + quad;            // global chunk 0..7
      const int cp = (cg ^ sw) << 3;              // swizzled LDS offset (shorts)
      bf16x8 af[4], bfr[4];
#pragma unroll
      for (int mt = 0; mt < 4; ++mt)
        af[mt] = *(const bf16x8*)(As + (size_t)(wm * 64 + mt * 16 + mfrag) * 64 + cp);
#pragma unroll
      for (int nt = 0; nt < 4; ++nt)
        bfr[nt] = *(const bf16x8*)(Bs + (size_t)(wn * 64 + nt * 16 + mfrag) * 64 + cp);
#pragma unroll
      for (int mt = 0; mt < 4; ++mt)
#pragma unroll
        for (int nt = 0; nt < 4; ++nt)
          acc[mt][nt] = __builtin_amdgcn_mfma_f32_16x16x32_bf16(
              af[mt], bfr[nt], acc[mt][nt], 0, 0, 0);
    }
    __syncthreads();
  }

  const int ccol = lane & 15;
  const int crow = (lane >> 4) * 4;
#pragma unroll
  for (int nt = 0; nt < 4; ++nt) {
    const int col = n0 + wn * 64 + nt * 16 + ccol;
    const float bv = bias[col];
#pragma unroll
    for (int mt = 0; mt < 4; ++mt) {
#pragma unroll
      for (int r = 0; r < 4; ++r) {
        const int row = m0 + wm * 64 + mt * 16 + crow + r;
        const float val = acc[mt][nt][r] + bv;
        if (OUT_BF16)
          ((unsigned short*)Cv)[(size_t)row * N + col] = f2bf(val);
        else
          ((float*)Cv)[(size_t)row * N + col] = val;
      }
    }
  }
}

// ---------------------------------------------------------------------------
// Banded causal attention via bf16 MFMA, fp32 softmax. XOR-swizzled LDS.
// ---------------------------------------------------------------------------
#define PSTR 68
__global__ __launch_bounds__(256) void attn_mfma(
    const unsigned short* __restrict__ qkv, unsigned short* __restrict__ y) {
  __shared__ unsigned short Qs[64 * 64];   // [qrow][d]  bf16, swizzled
  __shared__ unsigned short Ks[64 * 64];   // [key][d]   bf16, swizzled
  __shared__ unsigned short Vt[64 * 64];   // [d][key]   bf16, swizzled
  __shared__ float Pw[4][16 * PSTR];       // per-wave P [qrow16][key64]

  const int bid = blockIdx.x;
  const int qt  = bid & 3;
  const int h   = (bid >> 2) % HEADS;
  const int b   = bid / (4 * HEADS);
  const int t   = threadIdx.x;
  const int lane = t & 63;
  const int w    = t >> 6;
  const int quad = lane >> 4;
  const int m16  = lane & 15;
  const int sw   = m16 & 7;

  const size_t rowbase = (size_t)b * T_SEQ * (3 * C_DIM);
  const int qoff = h * HD;
  const int koff = C_DIM + h * HD;
  const int voff = 2 * C_DIM + h * HD;
  const int qg0  = qt * 64;

  const int lrow = lane >> 3;
  const int lcol = lane & 7;
  const int schunk = lcol ^ lrow;

  // ---- stage Q (64x64 bf16), swizzled ----
#pragma unroll
  for (int i = 0; i < 2; ++i) {
    const int inst = w * 2 + i;
    const int r = inst * 8 + lrow;
    const unsigned short* ga =
        qkv + rowbase + (size_t)(qg0 + r) * (3 * C_DIM) + qoff + schunk * 8;
    __builtin_amdgcn_global_load_lds((const gbl_void*)ga,
                                     (lds_void*)(Qs + inst * 512), 16, 0, 0);
  }

  float m_r[4], l_r[4];
  f32x4 yacc[4];
#pragma unroll
  for (int r = 0; r < 4; ++r) { m_r[r] = -1e30f; l_r[r] = 0.f; }
#pragma unroll
  for (int dt = 0; dt < 4; ++dt) yacc[dt] = (f32x4){0.f, 0.f, 0.f, 0.f};

  const int nchunks  = (qt == 0) ? 1 : 2;
  const int kb_first = (qt == 0) ? 0 : (qg0 - 64);
  const int qrow_base = qg0 + w * 16 + quad * 4;

  for (int ch = 0; ch < nchunks; ++ch) {
    const int kb = kb_first + ch * 64;

    __syncthreads();  // drain staging; protect Ks/Vt/Pw from prior reads

    // ---- stage K, swizzled ----
#pragma unroll
    for (int i = 0; i < 2; ++i) {
      const int inst = w * 2 + i;
      const int r = inst * 8 + lrow;
      const unsigned short* ga =
          qkv + rowbase + (size_t)(kb + r) * (3 * C_DIM) + koff + schunk * 8;
      __builtin_amdgcn_global_load_lds((const gbl_void*)ga,
                                       (lds_void*)(Ks + inst * 512), 16, 0, 0);
    }
    // ---- stage V transposed, swizzled: Vt[d][pos] = keychunk pos^(d&7) ----
    {
      const int vkey = t & 63;
      const int kc = vkey >> 3, ke = vkey & 7;
      const int vd0  = (t >> 6) * 16;
      const unsigned short* gv =
          qkv + rowbase + (size_t)(kb + vkey) * (3 * C_DIM) + voff + vd0;
#pragma unroll
      for (int u = 0; u < 4; ++u) {
        ushort4 vv = *(const ushort4*)(gv + u * 4);
#pragma unroll
        for (int jj = 0; jj < 4; ++jj) {
          const int d = vd0 + u * 4 + jj;
          const unsigned short val =
              (jj == 0) ? vv.x : (jj == 1) ? vv.y : (jj == 2) ? vv.z : vv.w;
          Vt[d * 64 + ((kc ^ (d & 7)) << 3) + ke] = val;
        }
      }
    }
    __syncthreads();

    // ---- QK^T: S[16q x 64key] ----
    f32x4 sacc[4];
#pragma unroll
    for (int nt = 0; nt < 4; ++nt) sacc[nt] = (f32x4){0.f, 0.f, 0.f, 0.f};
#pragma unroll
    for (int ks = 0; ks < 64; ks += 32) {
      const int cp = (((ks >> 3) + quad) ^ sw) << 3;
      bf16x8 aq = *(const bf16x8*)(Qs + (size_t)(w * 16 + m16) * 64 + cp);
#pragma unroll
      for (int nt = 0; nt < 4; ++nt) {
        bf16x8 kf = *(const bf16x8*)(Ks + (size_t)(nt * 16 + m16) * 64 + cp);
        sacc[nt] = __builtin_amdgcn_mfma_f32_16x16x32_bf16(aq, kf, sacc[nt], 0, 0, 0);
      }
    }

    // ---- scale + band mask (C-layout: row=quad*4+r, col=m16) ----
    float mc[4] = {-1e30f, -1e30f, -1e30f, -1e30f};
#pragma unroll
    for (int nt = 0; nt < 4; ++nt) {
      const int kg = kb + nt * 16 + m16;
#pragma unroll
      for (int r = 0; r < 4; ++r) {
        const int qg = qrow_base + r;
        const bool valid = (kg <= qg) && (qg - kg <= WIN);
        const float sv = valid ? (sacc[nt][r] * 0.125f) : -1e30f;
        sacc[nt][r] = sv;
        mc[r] = fmaxf(mc[r], sv);
      }
    }
#pragma unroll
    for (int r = 0; r < 4; ++r) {
#pragma unroll
      for (int x = 1; x <= 8; x <<= 1) mc[r] = fmaxf(mc[r], __shfl_xor(mc[r], x));
    }

    // ---- online softmax update ----
#pragma unroll
    for (int r = 0; r < 4; ++r) {
      const float mn    = fmaxf(m_r[r], mc[r]);
      const float alpha = __expf(m_r[r] - mn);
      m_r[r] = mn;
      l_r[r] *= alpha;
#pragma unroll
      for (int dt = 0; dt < 4; ++dt) yacc[dt][r] *= alpha;
      float ls = 0.f;
#pragma unroll
      for (int nt = 0; nt < 4; ++nt) {
        const float p = __expf(sacc[nt][r] - mn);
        sacc[nt][r] = p;
        ls += p;
      }
#pragma unroll
      for (int x = 1; x <= 8; x <<= 1) ls += __shfl_xor(ls, x);
      l_r[r] += ls;
    }

    // ---- write P (fp32) to per-wave LDS ----
#pragma unroll
    for (int nt = 0; nt < 4; ++nt)
#pragma unroll
      for (int r = 0; r < 4; ++r)
        Pw[w][(quad * 4 + r) * PSTR + nt * 16 + m16] = sacc[nt][r];
    __syncthreads();

    // ---- PV: A = P-frag (fp32->bf16), B = Vt-frag ----
#pragma unroll
    for (int ks = 0; ks < 64; ks += 32) {
      f32x4 pa = *(const f32x4*)(&Pw[w][m16 * PSTR + ks + quad * 8]);
      f32x4 pb = *(const f32x4*)(&Pw[w][m16 * PSTR + ks + quad * 8 + 4]);
      bf16x8 ap;
#pragma unroll
      for (int j = 0; j < 4; ++j) {
        ap[j]     = (__bf16)pa[j];
        ap[4 + j] = (__bf16)pb[j];
      }
      const int cp = (((ks >> 3) + quad) ^ sw) << 3;
#pragma unroll
      for (int dt = 0; dt < 4; ++dt) {
        bf16x8 vf = *(const bf16x8*)(Vt + (size_t)(dt * 16 + m16) * 64 + cp);
        yacc[dt] = __builtin_amdgcn_mfma_f32_16x16x32_bf16(ap, vf, yacc[dt], 0, 0, 0);
      }
    }
  }

  // ---- epilogue: y(bf16) = yacc / l ----
  float inv[4];
#pragma unroll
  for (int r = 0; r < 4; ++r) inv[r] = 1.f / l_r[r];
#pragma unroll
  for (int dt = 0; dt < 4; ++dt) {
#pragma unroll
    for (int r = 0; r < 4; ++r) {
      const int row = qrow_base + r;
      y[((size_t)(b * T_SEQ + row)) * C_DIM + h * HD + dt * 16 + m16] =
          f2bf(yacc[dt][r] * inv[r]);
    }
  }
}

// ---------------------------------------------------------------------------
extern "C" void kernel_launch(void* const* d_in, const int* in_sizes, int n_in,
                              void* d_out, int out_size, void* d_ws, size_t ws_size,
                              hipStream_t stream) {
  const float* x      = (const float*)d_in[0];
  const float* W_attn = (const float*)d_in[1];
  const float* b_attn = (const float*)d_in[2];
  const float* W_proj = (const float*)d_in[3];
  const float* b_proj = (const float*)d_in[4];
  float* out = (float*)d_out;

  const int M = B_SZ * T_SEQ;  // 32768

  unsigned short* qkv_b = (unsigned short*)d_ws;            // M*1152 bf16
  unsigned short* y_b   = qkv_b + (size_t)M * (3 * C_DIM);  // M*384
  unsigned short* x_b   = y_b   + (size_t)M * C_DIM;        // M*384
  unsigned short* Wa_t  = x_b   + (size_t)M * C_DIM;        // 1152*384
  unsigned short* Wp_t  = Wa_t  + (size_t)(3 * C_DIM) * C_DIM;  // 384*384

  // 0) converts
  {
    int n4 = M * C_DIM / 4;
    convert_f32_bf16<<<n4 / 256, 256, 0, stream>>>(x, x_b, n4);
    transpose_convert<<<dim3((3 * C_DIM) / 32, C_DIM / 32), dim3(32, 8), 0, stream>>>(
        W_attn, Wa_t, C_DIM, 3 * C_DIM);
    transpose_convert<<<dim3(C_DIM / 32, C_DIM / 32), dim3(32, 8), 0, stream>>>(
        W_proj, Wp_t, C_DIM, C_DIM);
  }

  // 1) qkv(bf16) = x @ W_attn + b_attn   [32768 x 1152]
  gemm_mfma_bf16<true><<<dim3((3 * C_DIM) / 128, M / 128), 256, 0, stream>>>(
      x_b, Wa_t, b_attn, qkv_b, M, 3 * C_DIM, C_DIM);

  // 2) banded causal attention -> y(bf16) [32768 x 384]
  attn_mfma<<<dim3(B_SZ * HEADS * (T_SEQ / 64)), 256, 0, stream>>>(qkv_b, y_b);

  // 3) out(fp32) = y @ W_proj + b_proj   [32768 x 384]
  gemm_mfma_bf16<false><<<dim3(C_DIM / 128, M / 128), 256, 0, stream>>>(
      y_b, Wp_t, b_proj, out, M, C_DIM, C_DIM);
}

// Round 6
// 211.927 us; speedup vs baseline: 3.2729x; 1.0601x over previous
//
#include <hip/hip_runtime.h>

#define B_SZ   128
#define T_SEQ  256
#define C_DIM  384
#define HEADS  6
#define HD     64
#define WIN    64

typedef __bf16 bf16x8 __attribute__((ext_vector_type(8)));
typedef float  f32x4  __attribute__((ext_vector_type(4)));

typedef __attribute__((address_space(3))) void lds_void;
typedef __attribute__((address_space(1))) void gbl_void;

__device__ __forceinline__ unsigned short f2bf(float f) {
  unsigned u = __float_as_uint(f);
  u += 0x7FFFu + ((u >> 16) & 1u);   // RNE
  return (unsigned short)(u >> 16);
}

// ---------------------------------------------------------------------------
// fp32 -> bf16 elementwise convert (vectorized, n4 = nelems/4)
// ---------------------------------------------------------------------------
__global__ __launch_bounds__(256) void convert_f32_bf16(
    const float* __restrict__ in, unsigned short* __restrict__ out, int n4) {
  int i = blockIdx.x * blockDim.x + threadIdx.x;
  if (i < n4) {
    float4 v = ((const float4*)in)[i];
    ushort4 o;
    o.x = f2bf(v.x); o.y = f2bf(v.y); o.z = f2bf(v.z); o.w = f2bf(v.w);
    ((ushort4*)out)[i] = o;
  }
}

// ---------------------------------------------------------------------------
// W[K,N] fp32 -> Wt[N,K] bf16, 32x32 LDS tile transpose.
// ---------------------------------------------------------------------------
__global__ __launch_bounds__(256) void transpose_convert(
    const float* __restrict__ in, unsigned short* __restrict__ out,
    int K, int N) {
  __shared__ float tile[32][33];
  const int gx = blockIdx.x * 32;  // n
  const int gy = blockIdx.y * 32;  // k
  const int tx = threadIdx.x;      // 0..31
  const int ty = threadIdx.y;      // 0..7
#pragma unroll
  for (int r = ty; r < 32; r += 8)
    tile[r][tx] = in[(size_t)(gy + r) * N + gx + tx];
  __syncthreads();
#pragma unroll
  for (int r = ty; r < 32; r += 8)
    out[(size_t)(gx + r) * K + gy + tx] = f2bf(tile[tx][r]);
}

// ---------------------------------------------------------------------------
// bf16 MFMA GEMM: C[M,N] = A[M,K] @ Bt[N,K]^T + bias[N]
// 128x128 tile, BK=64, 4 waves (2x2), wave = 4x4 of 16x16x32 MFMA.
// XOR-swizzled LDS staging (bank-conflict-free frag reads).
// 1-D grid + XCD-grouped remap: contiguous M-panel slabs per XCD (L2 reuse).
// Epilogue: 2 half-passes through LDS (64x128 fp32, stride 132), coalesced
// vector stores (16x fewer store insts than per-reg scalar stores).
// ---------------------------------------------------------------------------
template <bool OUT_BF16>
__global__ __launch_bounds__(256) void gemm_mfma_bf16(
    const unsigned short* __restrict__ A,   // [M,K] bf16
    const unsigned short* __restrict__ Bt,  // [N,K] bf16
    const float* __restrict__ bias,
    void* __restrict__ Cv, int M, int N, int K, int tiles_n) {
  __shared__ __attribute__((aligned(16))) char smem_raw[64 * 132 * 4];  // 33792 B
  unsigned short* As = (unsigned short*)smem_raw;       // 128*64 shorts
  unsigned short* Bs = As + 128 * 64;                   // 128*64 shorts
  float* ep = (float*)smem_raw;                         // 64 x 132 fp32

  const int t    = threadIdx.x;
  const int lane = t & 63;
  const int w    = t >> 6;
  const int wm   = w & 1;
  const int wn   = w >> 1;

  // XCD-grouped remap: blocks id===x (mod 8) -> same XCD; give each XCD a
  // contiguous slab so the tiles_n blocks of an M-panel share one L2.
  const unsigned id    = blockIdx.x;
  const unsigned remap = (id & 7u) * (gridDim.x >> 3) + (id >> 3);
  const int by = remap / (unsigned)tiles_n;
  const int bx = remap % (unsigned)tiles_n;
  const int m0 = by * 128;
  const int n0 = bx * 128;

  const int lrow = lane >> 3;         // 0..7 row within 8-row slab
  const int lcol = lane & 7;          // 0..7 LDS 16B-position
  const int schunk = lcol ^ lrow;     // swizzled global chunk this lane fetches

  f32x4 acc[4][4];
#pragma unroll
  for (int i = 0; i < 4; ++i)
#pragma unroll
    for (int j = 0; j < 4; ++j) acc[i][j] = (f32x4){0.f, 0.f, 0.f, 0.f};

  const int mfrag = lane & 15;
  const int quad  = lane >> 4;
  const int sw    = mfrag & 7;

  for (int k0 = 0; k0 < K; k0 += 64) {
#pragma unroll
    for (int i = 0; i < 4; ++i) {
      const int inst = w * 4 + i;
      const int r = inst * 8 + lrow;
      const unsigned short* ga = A  + (size_t)(m0 + r) * K + k0 + schunk * 8;
      const unsigned short* gb = Bt + (size_t)(n0 + r) * K + k0 + schunk * 8;
      __builtin_amdgcn_global_load_lds((const gbl_void*)ga,
                                       (lds_void*)(As + inst * 512), 16, 0, 0);
      __builtin_amdgcn_global_load_lds((const gbl_void*)gb,
                                       (lds_void*)(Bs + inst * 512), 16, 0, 0);
    }
    __syncthreads();

#pragma unroll
    for (int ks = 0; ks < 64; ks += 32) {
      const int cp = (((ks >> 3) + quad) ^ sw) << 3;
      bf16x8 af[4], bfr[4];
#pragma unroll
      for (int mt = 0; mt < 4; ++mt)
        af[mt] = *(const bf16x8*)(As + (size_t)(wm * 64 + mt * 16 + mfrag) * 64 + cp);
#pragma unroll
      for (int nt = 0; nt < 4; ++nt)
        bfr[nt] = *(const bf16x8*)(Bs + (size_t)(wn * 64 + nt * 16 + mfrag) * 64 + cp);
#pragma unroll
      for (int mt = 0; mt < 4; ++mt)
#pragma unroll
        for (int nt = 0; nt < 4; ++nt)
          acc[mt][nt] = __builtin_amdgcn_mfma_f32_16x16x32_bf16(
              af[mt], bfr[nt], acc[mt][nt], 0, 0, 0);
    }
    __syncthreads();
  }
  // loop exits after a barrier: LDS free for epilogue reuse.

  // bias per nt at this lane's C column (col = n0 + wn*64 + nt*16 + mfrag)
  float bv[4];
#pragma unroll
  for (int nt = 0; nt < 4; ++nt) bv[nt] = bias[n0 + wn * 64 + nt * 16 + mfrag];

  // ---- epilogue: 2 half-passes (rows p*64..p*64+63) through LDS ----
#pragma unroll
  for (int p = 0; p < 2; ++p) {
    if (p) __syncthreads();  // pass-0 reads done before overwrite
    if (wm == p) {
#pragma unroll
      for (int mt = 0; mt < 4; ++mt)
#pragma unroll
        for (int nt = 0; nt < 4; ++nt)
#pragma unroll
          for (int r = 0; r < 4; ++r)
            ep[(mt * 16 + quad * 4 + r) * 132 + wn * 64 + nt * 16 + mfrag] =
                acc[mt][nt][r] + bv[nt];
    }
    __syncthreads();
    // 64 rows x 32 float4-chunks = 2048 chunks, 8 per thread, coalesced
#pragma unroll
    for (int cc = 0; cc < 8; ++cc) {
      const int chunk = cc * 256 + t;
      const int row = chunk >> 5;
      const int c4  = chunk & 31;
      f32x4 v = *(const f32x4*)(ep + row * 132 + c4 * 4);
      const int grow = m0 + p * 64 + row;
      const int gcol = n0 + c4 * 4;
      if (OUT_BF16) {
        ushort4 o;
        o.x = f2bf(v[0]); o.y = f2bf(v[1]); o.z = f2bf(v[2]); o.w = f2bf(v[3]);
        *(ushort4*)((unsigned short*)Cv + (size_t)grow * N + gcol) = o;
      } else {
        *(f32x4*)((float*)Cv + (size_t)grow * N + gcol) = v;
      }
    }
  }
}

// ---------------------------------------------------------------------------
// Banded causal attention via bf16 MFMA, fp32 softmax. XOR-swizzled LDS,
// XCD-grouped remap, vectorized epilogue through Pw.
// ---------------------------------------------------------------------------
#define PSTR 68
__global__ __launch_bounds__(256) void attn_mfma(
    const unsigned short* __restrict__ qkv, unsigned short* __restrict__ y) {
  __shared__ unsigned short Qs[64 * 64];   // [qrow][d]  bf16, swizzled
  __shared__ unsigned short Ks[64 * 64];   // [key][d]   bf16, swizzled
  __shared__ unsigned short Vt[64 * 64];   // [d][key]   bf16, swizzled
  __shared__ float Pw[4][16 * PSTR];       // per-wave P; reused as y-stage

  const unsigned id  = blockIdx.x;
  const unsigned bid = (id & 7u) * (gridDim.x >> 3) + (id >> 3);
  const int qt  = bid & 3;
  const int h   = (bid >> 2) % HEADS;
  const int b   = bid / (4 * HEADS);
  const int t   = threadIdx.x;
  const int lane = t & 63;
  const int w    = t >> 6;
  const int quad = lane >> 4;
  const int m16  = lane & 15;
  const int sw   = m16 & 7;

  const size_t rowbase = (size_t)b * T_SEQ * (3 * C_DIM);
  const int qoff = h * HD;
  const int koff = C_DIM + h * HD;
  const int voff = 2 * C_DIM + h * HD;
  const int qg0  = qt * 64;

  const int lrow = lane >> 3;
  const int lcol = lane & 7;
  const int schunk = lcol ^ lrow;

  // ---- stage Q (64x64 bf16), swizzled ----
#pragma unroll
  for (int i = 0; i < 2; ++i) {
    const int inst = w * 2 + i;
    const int r = inst * 8 + lrow;
    const unsigned short* ga =
        qkv + rowbase + (size_t)(qg0 + r) * (3 * C_DIM) + qoff + schunk * 8;
    __builtin_amdgcn_global_load_lds((const gbl_void*)ga,
                                     (lds_void*)(Qs + inst * 512), 16, 0, 0);
  }

  float m_r[4], l_r[4];
  f32x4 yacc[4];
#pragma unroll
  for (int r = 0; r < 4; ++r) { m_r[r] = -1e30f; l_r[r] = 0.f; }
#pragma unroll
  for (int dt = 0; dt < 4; ++dt) yacc[dt] = (f32x4){0.f, 0.f, 0.f, 0.f};

  const int nchunks  = (qt == 0) ? 1 : 2;
  const int kb_first = (qt == 0) ? 0 : (qg0 - 64);
  const int qrow_base = qg0 + w * 16 + quad * 4;

  for (int ch = 0; ch < nchunks; ++ch) {
    const int kb = kb_first + ch * 64;

    __syncthreads();  // drain staging; protect Ks/Vt/Pw from prior reads

    // ---- stage K, swizzled ----
#pragma unroll
    for (int i = 0; i < 2; ++i) {
      const int inst = w * 2 + i;
      const int r = inst * 8 + lrow;
      const unsigned short* ga =
          qkv + rowbase + (size_t)(kb + r) * (3 * C_DIM) + koff + schunk * 8;
      __builtin_amdgcn_global_load_lds((const gbl_void*)ga,
                                       (lds_void*)(Ks + inst * 512), 16, 0, 0);
    }
    // ---- stage V transposed, swizzled: Vt[d][pos] = keychunk pos^(d&7) ----
    {
      const int vkey = t & 63;
      const int kc = vkey >> 3, ke = vkey & 7;
      const int vd0  = (t >> 6) * 16;
      const unsigned short* gv =
          qkv + rowbase + (size_t)(kb + vkey) * (3 * C_DIM) + voff + vd0;
#pragma unroll
      for (int u = 0; u < 4; ++u) {
        ushort4 vv = *(const ushort4*)(gv + u * 4);
#pragma unroll
        for (int jj = 0; jj < 4; ++jj) {
          const int d = vd0 + u * 4 + jj;
          const unsigned short val =
              (jj == 0) ? vv.x : (jj == 1) ? vv.y : (jj == 2) ? vv.z : vv.w;
          Vt[d * 64 + ((kc ^ (d & 7)) << 3) + ke] = val;
        }
      }
    }
    __syncthreads();

    // ---- QK^T: S[16q x 64key] ----
    f32x4 sacc[4];
#pragma unroll
    for (int nt = 0; nt < 4; ++nt) sacc[nt] = (f32x4){0.f, 0.f, 0.f, 0.f};
#pragma unroll
    for (int ks = 0; ks < 64; ks += 32) {
      const int cp = (((ks >> 3) + quad) ^ sw) << 3;
      bf16x8 aq = *(const bf16x8*)(Qs + (size_t)(w * 16 + m16) * 64 + cp);
#pragma unroll
      for (int nt = 0; nt < 4; ++nt) {
        bf16x8 kf = *(const bf16x8*)(Ks + (size_t)(nt * 16 + m16) * 64 + cp);
        sacc[nt] = __builtin_amdgcn_mfma_f32_16x16x32_bf16(aq, kf, sacc[nt], 0, 0, 0);
      }
    }

    // ---- scale + band mask (C-layout: row=quad*4+r, col=m16) ----
    float mc[4] = {-1e30f, -1e30f, -1e30f, -1e30f};
#pragma unroll
    for (int nt = 0; nt < 4; ++nt) {
      const int kg = kb + nt * 16 + m16;
#pragma unroll
      for (int r = 0; r < 4; ++r) {
        const int qg = qrow_base + r;
        const bool valid = (kg <= qg) && (qg - kg <= WIN);
        const float sv = valid ? (sacc[nt][r] * 0.125f) : -1e30f;
        sacc[nt][r] = sv;
        mc[r] = fmaxf(mc[r], sv);
      }
    }
#pragma unroll
    for (int r = 0; r < 4; ++r) {
#pragma unroll
      for (int x = 1; x <= 8; x <<= 1) mc[r] = fmaxf(mc[r], __shfl_xor(mc[r], x));
    }

    // ---- online softmax update ----
#pragma unroll
    for (int r = 0; r < 4; ++r) {
      const float mn    = fmaxf(m_r[r], mc[r]);
      const float alpha = __expf(m_r[r] - mn);
      m_r[r] = mn;
      l_r[r] *= alpha;
#pragma unroll
      for (int dt = 0; dt < 4; ++dt) yacc[dt][r] *= alpha;
      float ls = 0.f;
#pragma unroll
      for (int nt = 0; nt < 4; ++nt) {
        const float p = __expf(sacc[nt][r] - mn);
        sacc[nt][r] = p;
        ls += p;
      }
#pragma unroll
      for (int x = 1; x <= 8; x <<= 1) ls += __shfl_xor(ls, x);
      l_r[r] += ls;
    }

    // ---- write P (fp32) to per-wave LDS ----
#pragma unroll
    for (int nt = 0; nt < 4; ++nt)
#pragma unroll
      for (int r = 0; r < 4; ++r)
        Pw[w][(quad * 4 + r) * PSTR + nt * 16 + m16] = sacc[nt][r];
    __syncthreads();

    // ---- PV: A = P-frag (fp32->bf16), B = Vt-frag ----
#pragma unroll
    for (int ks = 0; ks < 64; ks += 32) {
      f32x4 pa = *(const f32x4*)(&Pw[w][m16 * PSTR + ks + quad * 8]);
      f32x4 pb = *(const f32x4*)(&Pw[w][m16 * PSTR + ks + quad * 8 + 4]);
      bf16x8 ap;
#pragma unroll
      for (int j = 0; j < 4; ++j) {
        ap[j]     = (__bf16)pa[j];
        ap[4 + j] = (__bf16)pb[j];
      }
      const int cp = (((ks >> 3) + quad) ^ sw) << 3;
#pragma unroll
      for (int dt = 0; dt < 4; ++dt) {
        bf16x8 vf = *(const bf16x8*)(Vt + (size_t)(dt * 16 + m16) * 64 + cp);
        yacc[dt] = __builtin_amdgcn_mfma_f32_16x16x32_bf16(ap, vf, yacc[dt], 0, 0, 0);
      }
    }
  }

  // ---- epilogue: stage y/l into Pw (wave-local region), coalesced stores ----
  float* epy = &Pw[0][0];  // viewed as [64 rows][68]; rows w*16.. are Pw[w]
  float inv[4];
#pragma unroll
  for (int r = 0; r < 4; ++r) inv[r] = 1.f / l_r[r];
#pragma unroll
  for (int dt = 0; dt < 4; ++dt)
#pragma unroll
    for (int r = 0; r < 4; ++r)
      epy[(w * 16 + quad * 4 + r) * PSTR + dt * 16 + m16] = yacc[dt][r] * inv[r];
  __syncthreads();
  // 64 rows x 16 ushort4-chunks = 1024 chunks, 4 per thread
#pragma unroll
  for (int cc = 0; cc < 4; ++cc) {
    const int chunk = cc * 256 + t;
    const int row = chunk >> 4;
    const int c4  = chunk & 15;
    f32x4 v = *(const f32x4*)(epy + row * PSTR + c4 * 4);
    ushort4 o;
    o.x = f2bf(v[0]); o.y = f2bf(v[1]); o.z = f2bf(v[2]); o.w = f2bf(v[3]);
    *(ushort4*)(y + (size_t)(b * T_SEQ + qg0 + row) * C_DIM + h * HD + c4 * 4) = o;
  }
}

// ---------------------------------------------------------------------------
extern "C" void kernel_launch(void* const* d_in, const int* in_sizes, int n_in,
                              void* d_out, int out_size, void* d_ws, size_t ws_size,
                              hipStream_t stream) {
  const float* x      = (const float*)d_in[0];
  const float* W_attn = (const float*)d_in[1];
  const float* b_attn = (const float*)d_in[2];
  const float* W_proj = (const float*)d_in[3];
  const float* b_proj = (const float*)d_in[4];
  float* out = (float*)d_out;

  const int M = B_SZ * T_SEQ;  // 32768

  unsigned short* qkv_b = (unsigned short*)d_ws;            // M*1152 bf16
  unsigned short* y_b   = qkv_b + (size_t)M * (3 * C_DIM);  // M*384
  unsigned short* x_b   = y_b   + (size_t)M * C_DIM;        // M*384
  unsigned short* Wa_t  = x_b   + (size_t)M * C_DIM;        // 1152*384
  unsigned short* Wp_t  = Wa_t  + (size_t)(3 * C_DIM) * C_DIM;  // 384*384

  // 0) converts
  {
    int n4 = M * C_DIM / 4;
    convert_f32_bf16<<<n4 / 256, 256, 0, stream>>>(x, x_b, n4);
    transpose_convert<<<dim3((3 * C_DIM) / 32, C_DIM / 32), dim3(32, 8), 0, stream>>>(
        W_attn, Wa_t, C_DIM, 3 * C_DIM);
    transpose_convert<<<dim3(C_DIM / 32, C_DIM / 32), dim3(32, 8), 0, stream>>>(
        W_proj, Wp_t, C_DIM, C_DIM);
  }

  // 1) qkv(bf16) = x @ W_attn + b_attn   [32768 x 1152], 9x256 tiles
  gemm_mfma_bf16<true><<<dim3(9 * (M / 128)), 256, 0, stream>>>(
      x_b, Wa_t, b_attn, qkv_b, M, 3 * C_DIM, C_DIM, 9);

  // 2) banded causal attention -> y(bf16) [32768 x 384]
  attn_mfma<<<dim3(B_SZ * HEADS * (T_SEQ / 64)), 256, 0, stream>>>(qkv_b, y_b);

  // 3) out(fp32) = y @ W_proj + b_proj   [32768 x 384], 3x256 tiles
  gemm_mfma_bf16<false><<<dim3(3 * (M / 128)), 256, 0, stream>>>(
      y_b, Wp_t, b_proj, out, M, C_DIM, C_DIM, 3);
}

// Round 7
// 205.918 us; speedup vs baseline: 3.3684x; 1.0292x over previous
//
#include <hip/hip_runtime.h>

#define B_SZ   128
#define T_SEQ  256
#define C_DIM  384
#define HEADS  6
#define HD     64
#define WIN    64

typedef __bf16 bf16x8 __attribute__((ext_vector_type(8)));
typedef float  f32x4  __attribute__((ext_vector_type(4)));

typedef __attribute__((address_space(3))) void lds_void;
typedef __attribute__((address_space(1))) void gbl_void;

__device__ __forceinline__ unsigned short f2bf(float f) {
  unsigned u = __float_as_uint(f);
  u += 0x7FFFu + ((u >> 16) & 1u);   // RNE
  return (unsigned short)(u >> 16);
}

// ---------------------------------------------------------------------------
// fp32 -> bf16 elementwise convert (vectorized, n4 = nelems/4)
// ---------------------------------------------------------------------------
__global__ __launch_bounds__(256) void convert_f32_bf16(
    const float* __restrict__ in, unsigned short* __restrict__ out, int n4) {
  int i = blockIdx.x * blockDim.x + threadIdx.x;
  if (i < n4) {
    float4 v = ((const float4*)in)[i];
    ushort4 o;
    o.x = f2bf(v.x); o.y = f2bf(v.y); o.z = f2bf(v.z); o.w = f2bf(v.w);
    ((ushort4*)out)[i] = o;
  }
}

// ---------------------------------------------------------------------------
// W[K,N] fp32 -> Wt[N,K] bf16, 32x32 LDS tile transpose.
// ---------------------------------------------------------------------------
__global__ __launch_bounds__(256) void transpose_convert(
    const float* __restrict__ in, unsigned short* __restrict__ out,
    int K, int N) {
  __shared__ float tile[32][33];
  const int gx = blockIdx.x * 32;  // n
  const int gy = blockIdx.y * 32;  // k
  const int tx = threadIdx.x;      // 0..31
  const int ty = threadIdx.y;      // 0..7
#pragma unroll
  for (int r = ty; r < 32; r += 8)
    tile[r][tx] = in[(size_t)(gy + r) * N + gx + tx];
  __syncthreads();
#pragma unroll
  for (int r = ty; r < 32; r += 8)
    out[(size_t)(gx + r) * K + gy + tx] = f2bf(tile[tx][r]);
}

// ---------------------------------------------------------------------------
// bf16 MFMA GEMM: C[M,N] = A[M,K] @ Bt[N,K]^T + bias[N]
// 256x128 tile, BK=64, 4 waves stacked in M; wave = 64Mx128N = 4x8 of
// 16x16x32 MFMA (LDS read bytes/FLOP -25% vs 64x64 waves; 64 MFMA/barrier).
// XOR-swizzled LDS staging (conflict-free frag reads), XCD-grouped remap,
// 4-pass vectorized LDS epilogue.
// ---------------------------------------------------------------------------
template <bool OUT_BF16>
__global__ __launch_bounds__(256, 2) void gemm_mfma_bf16(
    const unsigned short* __restrict__ A,   // [M,K] bf16
    const unsigned short* __restrict__ Bt,  // [N,K] bf16
    const float* __restrict__ bias,
    void* __restrict__ Cv, int M, int N, int K, int tiles_n) {
  __shared__ __attribute__((aligned(16))) char smem_raw[48 * 1024];
  unsigned short* As = (unsigned short*)smem_raw;       // 256*64 shorts, 32 KB
  unsigned short* Bs = As + 256 * 64;                   // 128*64 shorts, 16 KB
  float* ep = (float*)smem_raw;                         // 64 x 132 fp32, 33.8 KB

  const int t    = threadIdx.x;
  const int lane = t & 63;
  const int w    = t >> 6;

  // XCD-grouped remap: consecutive slabs per XCD so same-M-panel blocks
  // share one L2.
  const unsigned id    = blockIdx.x;
  const unsigned remap = (id & 7u) * (gridDim.x >> 3) + (id >> 3);
  const int by = remap / (unsigned)tiles_n;
  const int bx = remap % (unsigned)tiles_n;
  const int m0 = by * 256;
  const int n0 = bx * 128;

  const int lrow = lane >> 3;         // 0..7 row within 8-row slab
  const int lcol = lane & 7;          // 0..7 LDS 16B-position
  const int schunk = lcol ^ lrow;     // swizzled global chunk this lane fetches

  f32x4 acc[4][8];
#pragma unroll
  for (int i = 0; i < 4; ++i)
#pragma unroll
    for (int j = 0; j < 8; ++j) acc[i][j] = (f32x4){0.f, 0.f, 0.f, 0.f};

  const int mfrag = lane & 15;
  const int quad  = lane >> 4;
  const int sw    = mfrag & 7;

  for (int k0 = 0; k0 < K; k0 += 64) {
    // ---- stage A (256x64): 32 slabs, 8/wave; B (128x64): 16 slabs, 4/wave
#pragma unroll
    for (int i = 0; i < 8; ++i) {
      const int inst = w * 8 + i;
      const int r = inst * 8 + lrow;
      const unsigned short* ga = A + (size_t)(m0 + r) * K + k0 + schunk * 8;
      __builtin_amdgcn_global_load_lds((const gbl_void*)ga,
                                       (lds_void*)(As + inst * 512), 16, 0, 0);
    }
#pragma unroll
    for (int i = 0; i < 4; ++i) {
      const int inst = w * 4 + i;
      const int r = inst * 8 + lrow;
      const unsigned short* gb = Bt + (size_t)(n0 + r) * K + k0 + schunk * 8;
      __builtin_amdgcn_global_load_lds((const gbl_void*)gb,
                                       (lds_void*)(Bs + inst * 512), 16, 0, 0);
    }
    __syncthreads();

#pragma unroll
    for (int ks = 0; ks < 64; ks += 32) {
      const int cp = (((ks >> 3) + quad) ^ sw) << 3;
      bf16x8 af[4], bfr[8];
#pragma unroll
      for (int mt = 0; mt < 4; ++mt)
        af[mt] = *(const bf16x8*)(As + (size_t)(w * 64 + mt * 16 + mfrag) * 64 + cp);
#pragma unroll
      for (int nt = 0; nt < 8; ++nt)
        bfr[nt] = *(const bf16x8*)(Bs + (size_t)(nt * 16 + mfrag) * 64 + cp);
#pragma unroll
      for (int mt = 0; mt < 4; ++mt)
#pragma unroll
        for (int nt = 0; nt < 8; ++nt)
          acc[mt][nt] = __builtin_amdgcn_mfma_f32_16x16x32_bf16(
              af[mt], bfr[nt], acc[mt][nt], 0, 0, 0);
    }
    __syncthreads();
  }
  // loop exits after a barrier: LDS free for epilogue reuse.

  float bv[8];
#pragma unroll
  for (int nt = 0; nt < 8; ++nt) bv[nt] = bias[n0 + nt * 16 + mfrag];

  // ---- epilogue: 4 passes; wave p dumps its 64 rows, all store coalesced ----
#pragma unroll
  for (int p = 0; p < 4; ++p) {
    if (p) __syncthreads();  // prior pass reads done before overwrite
    if (w == p) {
#pragma unroll
      for (int mt = 0; mt < 4; ++mt)
#pragma unroll
        for (int nt = 0; nt < 8; ++nt)
#pragma unroll
          for (int r = 0; r < 4; ++r)
            ep[(mt * 16 + quad * 4 + r) * 132 + nt * 16 + mfrag] =
                acc[mt][nt][r] + bv[nt];
    }
    __syncthreads();
    // 64 rows x 32 float4-chunks = 2048 chunks, 8 per thread, coalesced
#pragma unroll
    for (int cc = 0; cc < 8; ++cc) {
      const int chunk = cc * 256 + t;
      const int row = chunk >> 5;
      const int c4  = chunk & 31;
      f32x4 v = *(const f32x4*)(ep + row * 132 + c4 * 4);
      const int grow = m0 + p * 64 + row;
      const int gcol = n0 + c4 * 4;
      if (OUT_BF16) {
        ushort4 o;
        o.x = f2bf(v[0]); o.y = f2bf(v[1]); o.z = f2bf(v[2]); o.w = f2bf(v[3]);
        *(ushort4*)((unsigned short*)Cv + (size_t)grow * N + gcol) = o;
      } else {
        *(f32x4*)((float*)Cv + (size_t)grow * N + gcol) = v;
      }
    }
  }
}

// ---------------------------------------------------------------------------
// Banded causal attention via bf16 MFMA, fp32 softmax. XOR-swizzled LDS,
// XCD-grouped remap, vectorized epilogue through Pw.
// ---------------------------------------------------------------------------
#define PSTR 68
__global__ __launch_bounds__(256) void attn_mfma(
    const unsigned short* __restrict__ qkv, unsigned short* __restrict__ y) {
  __shared__ unsigned short Qs[64 * 64];   // [qrow][d]  bf16, swizzled
  __shared__ unsigned short Ks[64 * 64];   // [key][d]   bf16, swizzled
  __shared__ unsigned short Vt[64 * 64];   // [d][key]   bf16, swizzled
  __shared__ float Pw[4][16 * PSTR];       // per-wave P; reused as y-stage

  const unsigned id  = blockIdx.x;
  const unsigned bid = (id & 7u) * (gridDim.x >> 3) + (id >> 3);
  const int qt  = bid & 3;
  const int h   = (bid >> 2) % HEADS;
  const int b   = bid / (4 * HEADS);
  const int t   = threadIdx.x;
  const int lane = t & 63;
  const int w    = t >> 6;
  const int quad = lane >> 4;
  const int m16  = lane & 15;
  const int sw   = m16 & 7;

  const size_t rowbase = (size_t)b * T_SEQ * (3 * C_DIM);
  const int qoff = h * HD;
  const int koff = C_DIM + h * HD;
  const int voff = 2 * C_DIM + h * HD;
  const int qg0  = qt * 64;

  const int lrow = lane >> 3;
  const int lcol = lane & 7;
  const int schunk = lcol ^ lrow;

  // ---- stage Q (64x64 bf16), swizzled ----
#pragma unroll
  for (int i = 0; i < 2; ++i) {
    const int inst = w * 2 + i;
    const int r = inst * 8 + lrow;
    const unsigned short* ga =
        qkv + rowbase + (size_t)(qg0 + r) * (3 * C_DIM) + qoff + schunk * 8;
    __builtin_amdgcn_global_load_lds((const gbl_void*)ga,
                                     (lds_void*)(Qs + inst * 512), 16, 0, 0);
  }

  float m_r[4], l_r[4];
  f32x4 yacc[4];
#pragma unroll
  for (int r = 0; r < 4; ++r) { m_r[r] = -1e30f; l_r[r] = 0.f; }
#pragma unroll
  for (int dt = 0; dt < 4; ++dt) yacc[dt] = (f32x4){0.f, 0.f, 0.f, 0.f};

  const int nchunks  = (qt == 0) ? 1 : 2;
  const int kb_first = (qt == 0) ? 0 : (qg0 - 64);
  const int qrow_base = qg0 + w * 16 + quad * 4;

  for (int ch = 0; ch < nchunks; ++ch) {
    const int kb = kb_first + ch * 64;

    __syncthreads();  // drain staging; protect Ks/Vt from prior cross-wave reads

    // ---- stage K, swizzled ----
#pragma unroll
    for (int i = 0; i < 2; ++i) {
      const int inst = w * 2 + i;
      const int r = inst * 8 + lrow;
      const unsigned short* ga =
          qkv + rowbase + (size_t)(kb + r) * (3 * C_DIM) + koff + schunk * 8;
      __builtin_amdgcn_global_load_lds((const gbl_void*)ga,
                                       (lds_void*)(Ks + inst * 512), 16, 0, 0);
    }
    // ---- stage V transposed, swizzled: Vt[d][pos] = keychunk pos^(d&7) ----
    {
      const int vkey = t & 63;
      const int kc = vkey >> 3, ke = vkey & 7;
      const int vd0  = (t >> 6) * 16;
      const unsigned short* gv =
          qkv + rowbase + (size_t)(kb + vkey) * (3 * C_DIM) + voff + vd0;
#pragma unroll
      for (int u = 0; u < 4; ++u) {
        ushort4 vv = *(const ushort4*)(gv + u * 4);
#pragma unroll
        for (int jj = 0; jj < 4; ++jj) {
          const int d = vd0 + u * 4 + jj;
          const unsigned short val =
              (jj == 0) ? vv.x : (jj == 1) ? vv.y : (jj == 2) ? vv.z : vv.w;
          Vt[d * 64 + ((kc ^ (d & 7)) << 3) + ke] = val;
        }
      }
    }
    __syncthreads();

    // ---- QK^T: S[16q x 64key] ----
    f32x4 sacc[4];
#pragma unroll
    for (int nt = 0; nt < 4; ++nt) sacc[nt] = (f32x4){0.f, 0.f, 0.f, 0.f};
#pragma unroll
    for (int ks = 0; ks < 64; ks += 32) {
      const int cp = (((ks >> 3) + quad) ^ sw) << 3;
      bf16x8 aq = *(const bf16x8*)(Qs + (size_t)(w * 16 + m16) * 64 + cp);
#pragma unroll
      for (int nt = 0; nt < 4; ++nt) {
        bf16x8 kf = *(const bf16x8*)(Ks + (size_t)(nt * 16 + m16) * 64 + cp);
        sacc[nt] = __builtin_amdgcn_mfma_f32_16x16x32_bf16(aq, kf, sacc[nt], 0, 0, 0);
      }
    }

    // ---- scale + band mask (C-layout: row=quad*4+r, col=m16) ----
    float mc[4] = {-1e30f, -1e30f, -1e30f, -1e30f};
#pragma unroll
    for (int nt = 0; nt < 4; ++nt) {
      const int kg = kb + nt * 16 + m16;
#pragma unroll
      for (int r = 0; r < 4; ++r) {
        const int qg = qrow_base + r;
        const bool valid = (kg <= qg) && (qg - kg <= WIN);
        const float sv = valid ? (sacc[nt][r] * 0.125f) : -1e30f;
        sacc[nt][r] = sv;
        mc[r] = fmaxf(mc[r], sv);
      }
    }
#pragma unroll
    for (int r = 0; r < 4; ++r) {
#pragma unroll
      for (int x = 1; x <= 8; x <<= 1) mc[r] = fmaxf(mc[r], __shfl_xor(mc[r], x));
    }

    // ---- online softmax update ----
#pragma unroll
    for (int r = 0; r < 4; ++r) {
      const float mn    = fmaxf(m_r[r], mc[r]);
      const float alpha = __expf(m_r[r] - mn);
      m_r[r] = mn;
      l_r[r] *= alpha;
#pragma unroll
      for (int dt = 0; dt < 4; ++dt) yacc[dt][r] *= alpha;
      float ls = 0.f;
#pragma unroll
      for (int nt = 0; nt < 4; ++nt) {
        const float p = __expf(sacc[nt][r] - mn);
        sacc[nt][r] = p;
        ls += p;
      }
#pragma unroll
      for (int x = 1; x <= 8; x <<= 1) ls += __shfl_xor(ls, x);
      l_r[r] += ls;
    }

    // ---- write P (fp32) to per-wave LDS (wave-private: no barrier needed;
    //      in-wave DS ordering + compiler lgkmcnt guard the RAW) ----
#pragma unroll
    for (int nt = 0; nt < 4; ++nt)
#pragma unroll
      for (int r = 0; r < 4; ++r)
        Pw[w][(quad * 4 + r) * PSTR + nt * 16 + m16] = sacc[nt][r];

    // ---- PV: A = P-frag (fp32->bf16), B = Vt-frag ----
#pragma unroll
    for (int ks = 0; ks < 64; ks += 32) {
      f32x4 pa = *(const f32x4*)(&Pw[w][m16 * PSTR + ks + quad * 8]);
      f32x4 pb = *(const f32x4*)(&Pw[w][m16 * PSTR + ks + quad * 8 + 4]);
      bf16x8 ap;
#pragma unroll
      for (int j = 0; j < 4; ++j) {
        ap[j]     = (__bf16)pa[j];
        ap[4 + j] = (__bf16)pb[j];
      }
      const int cp = (((ks >> 3) + quad) ^ sw) << 3;
#pragma unroll
      for (int dt = 0; dt < 4; ++dt) {
        bf16x8 vf = *(const bf16x8*)(Vt + (size_t)(dt * 16 + m16) * 64 + cp);
        yacc[dt] = __builtin_amdgcn_mfma_f32_16x16x32_bf16(ap, vf, yacc[dt], 0, 0, 0);
      }
    }
  }

  // ---- epilogue: stage y/l into Pw (wave-local region), coalesced stores ----
  float* epy = &Pw[0][0];  // viewed as [64 rows][68]; rows w*16.. are Pw[w]
  float inv[4];
#pragma unroll
  for (int r = 0; r < 4; ++r) inv[r] = 1.f / l_r[r];
#pragma unroll
  for (int dt = 0; dt < 4; ++dt)
#pragma unroll
    for (int r = 0; r < 4; ++r)
      epy[(w * 16 + quad * 4 + r) * PSTR + dt * 16 + m16] = yacc[dt][r] * inv[r];
  __syncthreads();
  // 64 rows x 16 ushort4-chunks = 1024 chunks, 4 per thread
#pragma unroll
  for (int cc = 0; cc < 4; ++cc) {
    const int chunk = cc * 256 + t;
    const int row = chunk >> 4;
    const int c4  = chunk & 15;
    f32x4 v = *(const f32x4*)(epy + row * PSTR + c4 * 4);
    ushort4 o;
    o.x = f2bf(v[0]); o.y = f2bf(v[1]); o.z = f2bf(v[2]); o.w = f2bf(v[3]);
    *(ushort4*)(y + (size_t)(b * T_SEQ + qg0 + row) * C_DIM + h * HD + c4 * 4) = o;
  }
}

// ---------------------------------------------------------------------------
extern "C" void kernel_launch(void* const* d_in, const int* in_sizes, int n_in,
                              void* d_out, int out_size, void* d_ws, size_t ws_size,
                              hipStream_t stream) {
  const float* x      = (const float*)d_in[0];
  const float* W_attn = (const float*)d_in[1];
  const float* b_attn = (const float*)d_in[2];
  const float* W_proj = (const float*)d_in[3];
  const float* b_proj = (const float*)d_in[4];
  float* out = (float*)d_out;

  const int M = B_SZ * T_SEQ;  // 32768

  unsigned short* qkv_b = (unsigned short*)d_ws;            // M*1152 bf16
  unsigned short* y_b   = qkv_b + (size_t)M * (3 * C_DIM);  // M*384
  unsigned short* x_b   = y_b   + (size_t)M * C_DIM;        // M*384
  unsigned short* Wa_t  = x_b   + (size_t)M * C_DIM;        // 1152*384
  unsigned short* Wp_t  = Wa_t  + (size_t)(3 * C_DIM) * C_DIM;  // 384*384

  // 0) converts
  {
    int n4 = M * C_DIM / 4;
    convert_f32_bf16<<<n4 / 256, 256, 0, stream>>>(x, x_b, n4);
    transpose_convert<<<dim3((3 * C_DIM) / 32, C_DIM / 32), dim3(32, 8), 0, stream>>>(
        W_attn, Wa_t, C_DIM, 3 * C_DIM);
    transpose_convert<<<dim3(C_DIM / 32, C_DIM / 32), dim3(32, 8), 0, stream>>>(
        W_proj, Wp_t, C_DIM, C_DIM);
  }

  // 1) qkv(bf16) = x @ W_attn + b_attn   [32768 x 1152], 128x9 tiles of 256x128
  gemm_mfma_bf16<true><<<dim3(9 * (M / 256)), 256, 0, stream>>>(
      x_b, Wa_t, b_attn, qkv_b, M, 3 * C_DIM, C_DIM, 9);

  // 2) banded causal attention -> y(bf16) [32768 x 384]
  attn_mfma<<<dim3(B_SZ * HEADS * (T_SEQ / 64)), 256, 0, stream>>>(qkv_b, y_b);

  // 3) out(fp32) = y @ W_proj + b_proj   [32768 x 384], 128x3 tiles of 256x128
  gemm_mfma_bf16<false><<<dim3(3 * (M / 256)), 256, 0, stream>>>(
      y_b, Wp_t, b_proj, out, M, C_DIM, C_DIM, 3);
}